// Round 15
// baseline (218.136 us; speedup 1.0000x reference)
//
#include <hip/hip_runtime.h>
#include <stdint.h>

typedef __bf16 bf16;
typedef bf16 bf16x8 __attribute__((ext_vector_type(8)));
typedef bf16 bf16x4 __attribute__((ext_vector_type(4)));
typedef float f32x2 __attribute__((ext_vector_type(2)));
typedef float f32x4 __attribute__((ext_vector_type(4)));
typedef float f32x16 __attribute__((ext_vector_type(16)));

#define AS1 __attribute__((address_space(1)))
#define AS3 __attribute__((address_space(3)))

__device__ __forceinline__ void gll16(const void* g, void* l) {
    __builtin_amdgcn_global_load_lds((const AS1 unsigned int*)g,
                                     (AS3 unsigned int*)l, 16, 0, 0);
}

// native RTNE f32->bf16
__device__ __forceinline__ bf16 f2bf(float x) { return (bf16)x; }

// single-instruction v_exp_f32 (2^x)
__device__ __forceinline__ float fexp2(float x) { return __builtin_amdgcn_exp2f(x); }

// QK scale folded into Q projection: (1/(8+1e-6)) * log2(e)
#define QSCALE_LOG2E 0.18033685757f

// ---------------- QKV input casts (proven ~23us) ----------------
__global__ void k_castqkv(const float* __restrict__ Q, const float* __restrict__ K,
                          const float* __restrict__ V,
                          bf16* __restrict__ oq, bf16* __restrict__ ok, bf16* __restrict__ ov)
{
    const int z = blockIdx.y;
    const float* in = z == 0 ? Q : z == 1 ? K : V;
    bf16* out = z == 0 ? oq : z == 1 ? ok : ov;
    const int i = blockIdx.x * 256 + threadIdx.x;
    for (size_t j = (size_t)i * 4; j < 8388608u; j += (size_t)2048 * 256 * 4) {
        float4 v = *(const float4*)(in + j);
        bf16x4 o;
        o[0] = f2bf(v.x); o[1] = f2bf(v.y); o[2] = f2bf(v.z); o[3] = f2bf(v.w);
        *(bf16x4*)(out + j) = o;
    }
}

// ---------------- weight casts ----------------
__global__ void k_castw(const float* __restrict__ Wq, const float* __restrict__ Wk,
                        const float* __restrict__ Wv, const float* __restrict__ Wo,
                        const float* __restrict__ W1, const float* __restrict__ W2,
                        bf16* __restrict__ oq, bf16* __restrict__ ok, bf16* __restrict__ ov,
                        bf16* __restrict__ oo, bf16* __restrict__ o1, bf16* __restrict__ o2)
{
    const int z = blockIdx.y;
    const int idx = blockIdx.x * 256 + threadIdx.x;
    const float* src = z == 0 ? Wq : z == 1 ? Wk : z == 2 ? Wv : z == 3 ? Wo : z == 4 ? W1 : W2;
    bf16* dst = z == 0 ? oq : z == 1 ? ok : z == 2 ? ov : z == 3 ? oo : z == 4 ? o1 : o2;
    if (z < 4) {
        const int n = idx >> 9, k = idx & 511;
        dst[idx] = f2bf(src[(k << 9) + n]);
    } else {
        dst[idx] = f2bf(src[idx]);
    }
}

// ---------------- shared GEMM core (bf16 A): C[128,128] += A[M,K] * Bt[N,K]^T ----------------
__device__ __forceinline__ void gemm_core(const bf16* __restrict__ A,
                                          const bf16* __restrict__ Bt,
                                          const int K, bf16* As, bf16* Bs,
                                          const int bm, const int bn,
                                          f32x4 acc[4][4])
{
    const int tid  = threadIdx.x;
    const int lane = tid & 63;
    const int wave = tid >> 6;
    const int g    = lane >> 4;
    const int l15  = lane & 15;
    const int wm   = (wave >> 1) * 64;
    const int wn   = (wave & 1) * 64;

    const int srow = tid >> 2;
    const int sk   = (tid & 3) * 8;
    const size_t aoff0 = (size_t)(bm + srow) * K + sk;
    const size_t aoff1 = (size_t)(bm + 64 + srow) * K + sk;
    const size_t boff0 = (size_t)(bn + srow) * K + sk;
    const size_t boff1 = (size_t)(bn + 64 + srow) * K + sk;
    char* asb = (char*)As + wave * 1024;
    char* bsb = (char*)Bs + wave * 1024;

    for (int kt = 0; kt < K; kt += 32) {
        __syncthreads();
        gll16(A + aoff0 + kt, asb);
        gll16(A + aoff1 + kt, asb + 4096);
        gll16(Bt + boff0 + kt, bsb);
        gll16(Bt + boff1 + kt, bsb + 4096);
        __syncthreads();
        bf16x8 af[4], bfv[4];
#pragma unroll
        for (int mi = 0; mi < 4; ++mi)
            af[mi] = *(const bf16x8*)&As[(wm + mi * 16 + l15) * 32 + g * 8];
#pragma unroll
        for (int ni = 0; ni < 4; ++ni)
            bfv[ni] = *(const bf16x8*)&Bs[(wn + ni * 16 + l15) * 32 + g * 8];
#pragma unroll
        for (int mi = 0; mi < 4; ++mi)
#pragma unroll
            for (int ni = 0; ni < 4; ++ni)
                acc[mi][ni] = __builtin_amdgcn_mfma_f32_16x16x32_bf16(
                    af[mi], bfv[ni], acc[mi][ni], 0, 0, 0);
    }
}

// ---------------- generic epilogue GEMMs ----------------
// EPI 1: Cb = bf16(acc + residf)                  (W_o + fp32 Q residual -> Xbf)
// EPI 2: Cb = bf16(relu(acc + bias[col]))         (FFN1 -> H1)
// EPI 3: Cf = acc + bias[col] + float(residb)     (FFN2 + residual -> out)
template<int EPI>
__global__ __launch_bounds__(256)
void k_gemm(const bf16* __restrict__ A, const bf16* __restrict__ Bt,
            const float* __restrict__ bias, const float* __restrict__ residf,
            const bf16* __restrict__ residb,
            float* __restrict__ Cf, bf16* __restrict__ Cb,
            int M, int N, int K)
{
    __shared__ bf16 As[128 * 32];
    __shared__ bf16 Bs[128 * 32];
    const int bm = blockIdx.y * 128, bn = blockIdx.x * 128;
    f32x4 acc[4][4] = {};
    gemm_core(A, Bt, K, As, Bs, bm, bn, acc);

    const int tid  = threadIdx.x;
    const int lane = tid & 63;
    const int wave = tid >> 6;
    const int g    = lane >> 4;
    const int l15  = lane & 15;
    const int wm   = (wave >> 1) * 64;
    const int wn   = (wave & 1) * 64;
    const int col0 = bn + wn + l15;
#pragma unroll
    for (int ni = 0; ni < 4; ++ni) {
        const int col = col0 + ni * 16;
        float bv = 0.f;
        if constexpr (EPI == 2 || EPI == 3) bv = bias[col];
#pragma unroll
        for (int mi = 0; mi < 4; ++mi) {
#pragma unroll
            for (int r = 0; r < 4; ++r) {
                const int row = bm + wm + mi * 16 + 4 * g + r;
                const size_t idx = (size_t)row * N + col;
                float v = acc[mi][ni][r];
                if constexpr (EPI == 1) {
                    Cb[idx] = f2bf(v + residf[idx]);
                } else if constexpr (EPI == 2) {
                    Cb[idx] = f2bf(fmaxf(v + bv, 0.f));
                } else {
                    Cf[idx] = v + bv + (float)residb[idx];
                }
            }
        }
    }
}

// ---------------- projections = plain k_gemm clone ----------------
// z=0: Q natural [b][s][512], scaled by QSCALE_LOG2E
// z=1: K natural [b][s][512]
// z=2: V transposed Vt[bh][dv][2048] via 8B vector stores (4 consecutive s per store)
__global__ __launch_bounds__(256)
void k_proj(const bf16* __restrict__ Qb, const bf16* __restrict__ Kb, const bf16* __restrict__ Vb,
            const bf16* __restrict__ BQ, const bf16* __restrict__ BK, const bf16* __restrict__ BV,
            bf16* __restrict__ OQ, bf16* __restrict__ OK_, bf16* __restrict__ OV)
{
    __shared__ bf16 As[128 * 32];
    __shared__ bf16 Bs[128 * 32];
    const int z = blockIdx.z;
    const bf16* A  = z == 0 ? Qb : z == 1 ? Kb : Vb;
    const bf16* Bt = z == 0 ? BQ : z == 1 ? BK : BV;
    bf16* Cb       = z == 0 ? OQ : z == 1 ? OK_ : OV;
    const int bm = blockIdx.y * 128, bn = blockIdx.x * 128;
    f32x4 acc[4][4] = {};
    gemm_core(A, Bt, 512, As, Bs, bm, bn, acc);

    const int tid  = threadIdx.x;
    const int lane = tid & 63;
    const int wave = tid >> 6;
    const int g    = lane >> 4;
    const int l15  = lane & 15;
    const int wm   = (wave >> 1) * 64;
    const int wn   = (wave & 1) * 64;
    const int col0 = bn + wn + l15;
#pragma unroll
    for (int ni = 0; ni < 4; ++ni) {
        const int col = col0 + ni * 16;
        if (z < 2) {
            const float sc = (z == 0) ? QSCALE_LOG2E : 1.f;
#pragma unroll
            for (int mi = 0; mi < 4; ++mi)
#pragma unroll
                for (int r = 0; r < 4; ++r) {
                    const int row = bm + wm + mi * 16 + 4 * g + r;
                    Cb[(size_t)row * 512 + col] = f2bf(acc[mi][ni][r] * sc);
                }
        } else {
            const int hcol = col >> 6, dv = col & 63;
#pragma unroll
            for (int mi = 0; mi < 4; ++mi) {
                const int row = bm + wm + mi * 16 + 4 * g;     // r=0..3 consecutive s
                const int b2 = row >> 11, sl = row & 2047;
                const size_t addr = ((size_t)(b2 * 8 + hcol) * 64 + dv) * 2048 + sl;
                bf16x4 vv;
#pragma unroll
                for (int r = 0; r < 4; ++r) vv[r] = f2bf(acc[mi][ni][r]);
                *(bf16x4*)&Cb[addr] = vv;
            }
        }
    }
}

// ---------------- flash attention: natural-Q/K gather, Vt rows, QBLK=64/wave ----------------
// Qn: [b][s][512] bf16 (scaled); Kn: [b][s][512] bf16; Vt: [bh][dv][2048] bf16.
// K LDS image (fragment-ordered) built by per-lane SOURCE gather (16B chunks are
// dk-contiguous in natural K). V staged as [dv][64 keys] rows with 16B-granule XOR
// swizzle (^dv&7); PV A-fragments read as b64 pairs (4-way conflict, ~free).
__global__ __launch_bounds__(256, 2)
void k_attn(const bf16* __restrict__ Qn, const bf16* __restrict__ Kn,
            const bf16* __restrict__ Vt, bf16* __restrict__ O)
{
    __shared__ bf16 smem[16384];   // 2 bufs x (8KB K + 8KB V)
    const int tid = threadIdx.x;
    const int l   = tid & 63;
    const int w   = tid >> 6;
    const int h   = l >> 5;
    const int ql  = l & 31;
    // XCD-chunked swizzle: xcd = d&7; 8 bh per XCD
    const int d   = blockIdx.x;
    const int bh  = ((d >> 6) << 3) | (d & 7);
    const int qt  = (d >> 3) & 7;
    const int b   = bh >> 3, head = bh & 7;
    const int q0 = qt * 256 + w * 64;
    const int loff = l * 16;

    // Q fragments (B-operand) from natural layout, two 32-row groups
    bf16x8 qfA[4], qfB[4];
    {
        const size_t qrow = (size_t)(b * 2048 + q0 + ql) * 512 + head * 64;
#pragma unroll
        for (int ks = 0; ks < 4; ++ks) {
            qfA[ks] = *(const bf16x8*)&Qn[qrow + ks * 16 + h * 8];
            qfB[ks] = *(const bf16x8*)&Qn[qrow + (size_t)32 * 512 + ks * 16 + h * 8];
        }
    }

    f32x16 oA0 = {}, oA1 = {}, oB0 = {}, oB1 = {};
    float lrunA = 0.f, lrunB = 0.f;

    // K gather source (fragment slot tid / tid+256 -> natural addr, 16B contiguous)
    const int ks2 = tid >> 6, h2k = (tid >> 5) & 1, qlk = tid & 31;
    const bf16* ksrc = Kn + (size_t)(b * 2048 + qlk) * 512 + head * 64 + ks2 * 16 + h2k * 8;
    // V gather source: granule-swizzled rows of Vt
    const int dv1 = tid >> 3;
    const bf16* vsrc = Vt + ((size_t)bh * 64 + dv1) * 2048 + (((tid & 7) ^ (dv1 & 7)) << 3);

    char* kb0 = (char*)smem;
    char* kb1 = (char*)smem + 16384;
    const int wdst = w * 1024;

    auto stage = [&](int kvt, char* kb) {
        const bf16* ks = ksrc + (size_t)kvt * 64 * 512;
        const bf16* vs = vsrc + kvt * 64;
        gll16(ks,                      kb + wdst);
        gll16(ks + (size_t)32 * 512,   kb + 4096 + wdst);
        gll16(vs,                      kb + 8192 + wdst);
        gll16(vs + (size_t)32 * 2048,  kb + 12288 + wdst);
    };

    auto compute = [&](const char* kb) {
        // ---- S^T = K Q^T : each A-fragment read feeds both q-groups ----
        f32x16 sA0 = {}, sA1 = {}, sB0 = {}, sB1 = {};
        __builtin_amdgcn_s_setprio(1);
#pragma unroll
        for (int ks = 0; ks < 4; ++ks) {
            bf16x8 a0 = *(const bf16x8*)(kb + ks * 1024 + loff);
            bf16x8 a1 = *(const bf16x8*)(kb + 4096 + ks * 1024 + loff);
            sA0 = __builtin_amdgcn_mfma_f32_32x32x16_bf16(a0, qfA[ks], sA0, 0, 0, 0);
            sB0 = __builtin_amdgcn_mfma_f32_32x32x16_bf16(a0, qfB[ks], sB0, 0, 0, 0);
            sA1 = __builtin_amdgcn_mfma_f32_32x32x16_bf16(a1, qfA[ks], sA1, 0, 0, 0);
            sB1 = __builtin_amdgcn_mfma_f32_32x32x16_bf16(a1, qfB[ks], sB1, 0, 0, 0);
        }
        __builtin_amdgcn_s_setprio(0);

        // ---- exp2 + packed lane-local partial sums ----
        f32x2 pA = {0.f, 0.f}, pB = {0.f, 0.f};
#pragma unroll
        for (int r = 0; r < 16; r += 2) {
            sA0[r]     = fexp2(sA0[r]);
            sA0[r + 1] = fexp2(sA0[r + 1]);
            sA1[r]     = fexp2(sA1[r]);
            sA1[r + 1] = fexp2(sA1[r + 1]);
            pA += (f32x2){sA0[r], sA0[r + 1]};
            pA += (f32x2){sA1[r], sA1[r + 1]};
        }
#pragma unroll
        for (int r = 0; r < 16; r += 2) {
            sB0[r]     = fexp2(sB0[r]);
            sB0[r + 1] = fexp2(sB0[r + 1]);
            sB1[r]     = fexp2(sB1[r]);
            sB1[r + 1] = fexp2(sB1[r + 1]);
            pB += (f32x2){sB0[r], sB0[r + 1]};
            pB += (f32x2){sB1[r], sB1[r + 1]};
        }
        lrunA += pA[0] + pA[1];
        lrunB += pB[0] + pB[1];

        // ---- P fragments (C/D order -> B operand) ----
        bf16x8 pbA[4], pbB[4];
#pragma unroll
        for (int j = 0; j < 4; ++j) {
            const int ofs = 8 * (j & 1);
#pragma unroll
            for (int e = 0; e < 8; ++e) {
                pbA[j][e] = f2bf((j & 2) ? sA1[ofs + e] : sA0[ofs + e]);
                pbB[j][e] = f2bf((j & 2) ? sB1[ofs + e] : sB0[ofs + e]);
            }
        }

        // ---- O^T += V^T P : A-fragments as b64 pairs from swizzled Vt rows ----
        const char* vr = kb + 8192;
        const int sw = ql & 7;
        __builtin_amdgcn_s_setprio(1);
#pragma unroll
        for (int j = 0; j < 4; ++j) {
            union U8 { struct { bf16x4 lo, hi; } p; bf16x8 v; };
            U8 u0, u1;
            const int ga = (((2 * j)     ^ sw) << 4) + 8 * h;
            const int gb = (((2 * j + 1) ^ sw) << 4) + 8 * h;
            u0.p.lo = *(const bf16x4*)(vr + ql * 128 + ga);
            u0.p.hi = *(const bf16x4*)(vr + ql * 128 + gb);
            u1.p.lo = *(const bf16x4*)(vr + 4096 + ql * 128 + ga);
            u1.p.hi = *(const bf16x4*)(vr + 4096 + ql * 128 + gb);
            oA0 = __builtin_amdgcn_mfma_f32_32x32x16_bf16(u0.v, pbA[j], oA0, 0, 0, 0);
            oB0 = __builtin_amdgcn_mfma_f32_32x32x16_bf16(u0.v, pbB[j], oB0, 0, 0, 0);
            oA1 = __builtin_amdgcn_mfma_f32_32x32x16_bf16(u1.v, pbA[j], oA1, 0, 0, 0);
            oB1 = __builtin_amdgcn_mfma_f32_32x32x16_bf16(u1.v, pbB[j], oB1, 0, 0, 0);
        }
        __builtin_amdgcn_s_setprio(0);
    };

    stage(0, kb0);
    __syncthreads();
    for (int kvt = 0; kvt < 32; kvt += 2) {
        if (kvt + 1 < 32) stage(kvt + 1, kb1);
        compute(kb0);
        __syncthreads();
        if (kvt + 2 < 32) stage(kvt + 2, kb0);
        compute(kb1);
        __syncthreads();
    }

    // ---- epilogue per q-group: normalize, transpose via per-wave LDS, store ----
    char* ot = (char*)smem + w * 4096;
    const int qr = l >> 1;
    const int dh4 = (l & 1) * 4;
    auto epi = [&](const f32x16& e0, const f32x16& e1, float lr, int qg) {
        lr += __shfl_xor(lr, 32);
        const float inv = 1.f / lr;
#pragma unroll
        for (int dvt = 0; dvt < 2; ++dvt) {
#pragma unroll
            for (int r = 0; r < 16; ++r) {
                const int dv = dvt * 32 + (r & 3) + 8 * (r >> 2) + 4 * h;
                const float val = (dvt ? e1[r] : e0[r]) * inv;
                *(bf16*)(ot + ql * 128 + ((((dv >> 3) ^ (ql & 7)) << 4) | ((dv & 7) << 1))) = f2bf(val);
            }
        }
        const size_t ob = ((size_t)b * 2048 + qg + qr) * 512 + head * 64 + (size_t)dh4 * 8;
#pragma unroll
        for (int B = 0; B < 4; ++B) {
            bf16x8 v = *(const bf16x8*)(ot + qr * 128 + (((dh4 + B) ^ (qr & 7)) << 4));
            *(bf16x8*)&O[ob + B * 8] = v;
        }
    };
    epi(oA0, oA1, lrunA, q0);
    epi(oB0, oB1, lrunB, q0 + 32);
}

// ---------------- launch ----------------
extern "C" void kernel_launch(void* const* d_in, const int* in_sizes, int n_in,
                              void* d_out, int out_size, void* d_ws, size_t ws_size,
                              hipStream_t stream)
{
    const float* Q  = (const float*)d_in[0];
    const float* K  = (const float*)d_in[1];
    const float* V  = (const float*)d_in[2];
    const float* Wq = (const float*)d_in[3];
    const float* Wk = (const float*)d_in[4];
    const float* Wv = (const float*)d_in[5];
    const float* Wo = (const float*)d_in[6];
    const float* W1 = (const float*)d_in[7];
    const float* b1 = (const float*)d_in[8];
    const float* W2 = (const float*)d_in[9];
    const float* b2 = (const float*)d_in[10];
    float* out = (float*)d_out;

    const int M = 8 * 2048;                 // 16384 rows
    const size_t TN = (size_t)M * 512;      // 8388608 elems
    const int WN = 512 * 512;               // 262144

    char* ws = (char*)d_ws;
    bf16* Qbf  = (bf16*)ws;  // bf16 casts of inputs
    bf16* Kbf  = Qbf + TN;
    bf16* Vbf  = Kbf + TN;
    bf16* Qpn  = Vbf + TN;   // Q-proj natural, scaled
    bf16* Kpn  = Qpn + TN;   // K-proj natural
    bf16* Vtn  = Kpn + TN;   // V-proj transposed [bh][dv][2048]
    bf16* Vatt = Vtn + TN;
    bf16* H1   = Vatt + TN;
    bf16* Wqt  = H1 + TN;
    bf16* Wkt  = Wqt + WN;
    bf16* Wvt  = Wkt + WN;
    bf16* Wot  = Wvt + WN;
    bf16* W1b  = Wot + WN;
    bf16* W2b  = W1b + WN;
    bf16* Xbf  = Qbf;           // alias: Qbf dead after projections

    // casts
    k_castqkv<<<dim3(2048, 3), 256, 0, stream>>>(Q, K, V, Qbf, Kbf, Vbf);
    k_castw<<<dim3(1024, 6), 256, 0, stream>>>(Wq, Wk, Wv, Wo, W1, W2,
                                               Wqt, Wkt, Wvt, Wot, W1b, W2b);

    // projections: plain gemms -> natural Q (scaled), natural K, transposed V
    k_proj<<<dim3(4, 128, 3), 256, 0, stream>>>(Qbf, Kbf, Vbf, Wqt, Wkt, Wvt,
                                                Qpn, Kpn, Vtn);

    // attention (512 blocks, 2/CU)
    k_attn<<<512, 256, 0, stream>>>(Qpn, Kpn, Vtn, Vatt);

    dim3 gg(4, 128);
    // W_o + residual(Q fp32) -> Xbf
    k_gemm<1><<<gg, 256, 0, stream>>>(Vatt, Wot, nullptr, Q, nullptr, nullptr, Xbf, M, 512, 512);
    // FFN1: relu(Xbf W1^T + b1) -> H1
    k_gemm<2><<<gg, 256, 0, stream>>>(Xbf, W1b, b1, nullptr, nullptr, nullptr, H1, M, 512, 512);
    // FFN2: H1 W2^T + b2 + Xbf -> out
    k_gemm<3><<<gg, 256, 0, stream>>>(H1, W2b, b2, nullptr, Xbf, out, nullptr, M, 512, 512);
}

// Round 16
// 204.671 us; speedup vs baseline: 1.0658x; 1.0658x over previous
//
#include <hip/hip_runtime.h>
#include <stdint.h>

typedef __bf16 bf16;
typedef bf16 bf16x8 __attribute__((ext_vector_type(8)));
typedef bf16 bf16x4 __attribute__((ext_vector_type(4)));
typedef float f32x2 __attribute__((ext_vector_type(2)));
typedef float f32x4 __attribute__((ext_vector_type(4)));
typedef float f32x16 __attribute__((ext_vector_type(16)));

#define AS1 __attribute__((address_space(1)))
#define AS3 __attribute__((address_space(3)))

__device__ __forceinline__ void gll16(const void* g, void* l) {
    __builtin_amdgcn_global_load_lds((const AS1 unsigned int*)g,
                                     (AS3 unsigned int*)l, 16, 0, 0);
}

// native RTNE f32->bf16
__device__ __forceinline__ bf16 f2bf(float x) { return (bf16)x; }

// single-instruction v_exp_f32 (2^x)
__device__ __forceinline__ float fexp2(float x) { return __builtin_amdgcn_exp2f(x); }

// QK scale folded into Q projection: (1/(8+1e-6)) * log2(e)
#define QSCALE_LOG2E 0.18033685757f

// ---------------- weight casts ----------------
// z<4: transpose-cast via LDS 64x64 tile (coalesced both sides); z>=4: straight copy
__global__ void k_castw(const float* __restrict__ Wq, const float* __restrict__ Wk,
                        const float* __restrict__ Wv, const float* __restrict__ Wo,
                        const float* __restrict__ W1, const float* __restrict__ W2,
                        bf16* __restrict__ oq, bf16* __restrict__ ok, bf16* __restrict__ ov,
                        bf16* __restrict__ oo, bf16* __restrict__ o1, bf16* __restrict__ o2)
{
    __shared__ bf16 L[64][65];
    const int z = blockIdx.y;
    const int t = threadIdx.x;
    const float* src = z == 0 ? Wq : z == 1 ? Wk : z == 2 ? Wv : z == 3 ? Wo : z == 4 ? W1 : W2;
    bf16* dst = z == 0 ? oq : z == 1 ? ok : z == 2 ? ov : z == 3 ? oo : z == 4 ? o1 : o2;
    if (z < 4) {
        const int tr = blockIdx.x >> 3, tc = blockIdx.x & 7;   // 64x64 tile
        const int r = t >> 2, c0 = (t & 3) * 16;
#pragma unroll
        for (int i = 0; i < 4; ++i) {
            float4 v = *(const float4*)(src + (size_t)(tr * 64 + r) * 512 + tc * 64 + c0 + i * 4);
            L[r][c0 + i * 4 + 0] = f2bf(v.x);
            L[r][c0 + i * 4 + 1] = f2bf(v.y);
            L[r][c0 + i * 4 + 2] = f2bf(v.z);
            L[r][c0 + i * 4 + 3] = f2bf(v.w);
        }
        __syncthreads();
        const int c2 = t >> 2, r0 = (t & 3) * 16;
        bf16* d = dst + (size_t)(tc * 64 + c2) * 512 + tr * 64 + r0;
#pragma unroll
        for (int i = 0; i < 16; ++i) d[i] = L[r0 + i][c2];
    } else {
        const size_t base = (size_t)blockIdx.x * 4096 + t * 16;
#pragma unroll
        for (int i = 0; i < 4; ++i) {
            float4 v = *(const float4*)(src + base + i * 4);
            bf16x4 o;
            o[0] = f2bf(v.x); o[1] = f2bf(v.y); o[2] = f2bf(v.z); o[3] = f2bf(v.w);
            *(bf16x4*)(dst + base + i * 4) = o;
        }
    }
}

// ---------------- shared GEMM core (bf16 A): C[128,128] += A[M,K] * Bt[N,K]^T ----------------
__device__ __forceinline__ void gemm_core(const bf16* __restrict__ A,
                                          const bf16* __restrict__ Bt,
                                          const int K, bf16* As, bf16* Bs,
                                          const int bm, const int bn,
                                          f32x4 acc[4][4])
{
    const int tid  = threadIdx.x;
    const int lane = tid & 63;
    const int wave = tid >> 6;
    const int g    = lane >> 4;
    const int l15  = lane & 15;
    const int wm   = (wave >> 1) * 64;
    const int wn   = (wave & 1) * 64;

    const int srow = tid >> 2;
    const int sk   = (tid & 3) * 8;
    const size_t aoff0 = (size_t)(bm + srow) * K + sk;
    const size_t aoff1 = (size_t)(bm + 64 + srow) * K + sk;
    const size_t boff0 = (size_t)(bn + srow) * K + sk;
    const size_t boff1 = (size_t)(bn + 64 + srow) * K + sk;
    char* asb = (char*)As + wave * 1024;
    char* bsb = (char*)Bs + wave * 1024;

    for (int kt = 0; kt < K; kt += 32) {
        __syncthreads();
        gll16(A + aoff0 + kt, asb);
        gll16(A + aoff1 + kt, asb + 4096);
        gll16(Bt + boff0 + kt, bsb);
        gll16(Bt + boff1 + kt, bsb + 4096);
        __syncthreads();
        bf16x8 af[4], bfv[4];
#pragma unroll
        for (int mi = 0; mi < 4; ++mi)
            af[mi] = *(const bf16x8*)&As[(wm + mi * 16 + l15) * 32 + g * 8];
#pragma unroll
        for (int ni = 0; ni < 4; ++ni)
            bfv[ni] = *(const bf16x8*)&Bs[(wn + ni * 16 + l15) * 32 + g * 8];
#pragma unroll
        for (int mi = 0; mi < 4; ++mi)
#pragma unroll
            for (int ni = 0; ni < 4; ++ni)
                acc[mi][ni] = __builtin_amdgcn_mfma_f32_16x16x32_bf16(
                    af[mi], bfv[ni], acc[mi][ni], 0, 0, 0);
    }
}

// ---------------- generic epilogue GEMMs ----------------
template<int EPI>
__global__ __launch_bounds__(256)
void k_gemm(const bf16* __restrict__ A, const bf16* __restrict__ Bt,
            const float* __restrict__ bias, const float* __restrict__ residf,
            const bf16* __restrict__ residb,
            float* __restrict__ Cf, bf16* __restrict__ Cb,
            int M, int N, int K)
{
    __shared__ bf16 As[128 * 32];
    __shared__ bf16 Bs[128 * 32];
    const int bm = blockIdx.y * 128, bn = blockIdx.x * 128;
    f32x4 acc[4][4] = {};
    gemm_core(A, Bt, K, As, Bs, bm, bn, acc);

    const int tid  = threadIdx.x;
    const int lane = tid & 63;
    const int wave = tid >> 6;
    const int g    = lane >> 4;
    const int l15  = lane & 15;
    const int wm   = (wave >> 1) * 64;
    const int wn   = (wave & 1) * 64;
    const int col0 = bn + wn + l15;
#pragma unroll
    for (int ni = 0; ni < 4; ++ni) {
        const int col = col0 + ni * 16;
        float bv = 0.f;
        if constexpr (EPI == 2 || EPI == 3) bv = bias[col];
#pragma unroll
        for (int mi = 0; mi < 4; ++mi) {
#pragma unroll
            for (int r = 0; r < 4; ++r) {
                const int row = bm + wm + mi * 16 + 4 * g + r;
                const size_t idx = (size_t)row * N + col;
                float v = acc[mi][ni][r];
                if constexpr (EPI == 1) {
                    Cb[idx] = f2bf(v + residf[idx]);
                } else if constexpr (EPI == 2) {
                    Cb[idx] = f2bf(fmaxf(v + bv, 0.f));
                } else {
                    Cf[idx] = v + bv + (float)residb[idx];
                }
            }
        }
    }
}

// ---------------- fused cast+projection (round-13 structure), one Z per launch ----------------
// 128x128 tile, 256 threads, single-buffer 2-barrier loop. A fp32 via gll16 with
// source-swizzled 16B chunks; fragments = 2x float4 + cvt. B staged as k_gemm.
// XCD-grouped: per launch, each XCD slot x gets 16 consecutive bm x 4 bn blocks.
// Epilogue: LDS-image scatter + contiguous copy-out.
// Z: 0=Q (scaled), 1=K frag-ordered, 2=V frag-ordered.
template<int Z>
__global__ __launch_bounds__(256)
void k_projZ(const float* __restrict__ A, const bf16* __restrict__ Bt,
             bf16* __restrict__ Cb)
{
    __shared__ char SMRAW[24576];        // 16KB fp32 A + 8KB bf16 B; image reuses A

    const int dd = blockIdx.x;           // 512 blocks
    const int x = dd & 7, q = dd >> 3;
    const int bn = (q & 3) * 128;
    const int bm = (x * 16 + (q >> 2)) * 128;

    bf16* Bs = (bf16*)(SMRAW + 16384);
    const int tid  = threadIdx.x;
    const int lane = tid & 63;
    const int wave = tid >> 6;
    const int g    = lane >> 4;
    const int l15  = lane & 15;
    const int wm   = (wave >> 1) * 64;
    const int wn   = (wave & 1) * 64;

    const int krow = tid >> 3, kc = tid & 7;
    const size_t aoff = (size_t)(bm + krow) * 512 + ((kc ^ (krow & 7)) << 2);
    const int srow = tid >> 2;
    const int sk   = (tid & 3) * 8;
    const size_t boff0 = (size_t)(bn + srow) * 512 + sk;
    const size_t boff1 = (size_t)(bn + 64 + srow) * 512 + sk;

    f32x4 acc[4][4] = {};

    for (int kt = 0; kt < 512; kt += 32) {
        __syncthreads();
#pragma unroll
        for (int j = 0; j < 4; ++j)
            gll16(A + aoff + j * 16384 + kt, SMRAW + j * 4096 + tid * 16);
        gll16(Bt + boff0 + kt, (char*)Bs + wave * 1024);
        gll16(Bt + boff1 + kt, (char*)Bs + wave * 1024 + 4096);
        __syncthreads();
        bf16x8 af[4], bfv[4];
#pragma unroll
        for (int mi = 0; mi < 4; ++mi) {
            const int row = wm + mi * 16 + l15;
            const int r7 = row & 7;
            float4 lo = *(const float4*)(SMRAW + row * 128 + (((2 * g) ^ r7) << 4));
            float4 hi = *(const float4*)(SMRAW + row * 128 + (((2 * g + 1) ^ r7) << 4));
            af[mi][0] = f2bf(lo.x); af[mi][1] = f2bf(lo.y);
            af[mi][2] = f2bf(lo.z); af[mi][3] = f2bf(lo.w);
            af[mi][4] = f2bf(hi.x); af[mi][5] = f2bf(hi.y);
            af[mi][6] = f2bf(hi.z); af[mi][7] = f2bf(hi.w);
        }
#pragma unroll
        for (int ni = 0; ni < 4; ++ni)
            bfv[ni] = *(const bf16x8*)&Bs[(wn + ni * 16 + l15) * 32 + g * 8];
#pragma unroll
        for (int mi = 0; mi < 4; ++mi)
#pragma unroll
            for (int ni = 0; ni < 4; ++ni)
                acc[mi][ni] = __builtin_amdgcn_mfma_f32_16x16x32_bf16(
                    af[mi], bfv[ni], acc[mi][ni], 0, 0, 0);
    }

    // ---- epilogue: LDS-image scatter + contiguous copy-out ----
    const int bb = bm >> 11;
    const int s0 = bm & 2047;
    __syncthreads();
#pragma unroll
    for (int p = 0; p < 2; ++p) {
        if ((wave >> 1) == p) {
            if constexpr (Z == 0) {
#pragma unroll
                for (int ni = 0; ni < 4; ++ni) {
                    const int col = wn + ni * 16 + l15;
                    const int hh = col >> 6, dk = col & 63;
                    char* img = SMRAW + hh * 8192;
#pragma unroll
                    for (int mi = 0; mi < 4; ++mi)
#pragma unroll
                        for (int r = 0; r < 4; ++r) {
                            const int sl = mi * 16 + 4 * g + r;
                            *(bf16*)(img + (sl * 64 + dk) * 2) =
                                f2bf(acc[mi][ni][r] * QSCALE_LOG2E);
                        }
                }
            } else if constexpr (Z == 1) {
#pragma unroll
                for (int ni = 0; ni < 4; ++ni) {
                    const int col = wn + ni * 16 + l15;
                    const int hh = col >> 6, dk = col & 63;
                    const int ks = dk >> 4, h2 = (dk >> 3) & 1, e = dk & 7;
                    char* img = SMRAW + hh * 8192;
#pragma unroll
                    for (int mi = 0; mi < 4; ++mi)
#pragma unroll
                        for (int r = 0; r < 4; ++r) {
                            const int sl = mi * 16 + 4 * g + r;
                            const int t2 = sl >> 5, ql = sl & 31;
                            *(bf16*)(img + (((t2 * 4 + ks) * 64 + h2 * 32 + ql) * 8 + e) * 2) =
                                f2bf(acc[mi][ni][r]);
                        }
                }
            } else {
#pragma unroll
                for (int ni = 0; ni < 4; ++ni) {
                    const int col = wn + ni * 16 + l15;
                    const int hh = col >> 6, dv = col & 63;
                    const int dvt = dv >> 5, ql = dv & 31;
                    char* img = SMRAW + hh * 8192;
#pragma unroll
                    for (int mi = 0; mi < 4; ++mi)
#pragma unroll
                        for (int r = 0; r < 4; ++r) {
                            const int sl = mi * 16 + 4 * g + r;
                            const int ktile = sl >> 4, kk = sl & 15;
                            const int h2 = (kk >> 2) & 1;
                            const int e = (kk & 3) | ((kk >> 3) << 2);
                            *(bf16*)(img + (((dvt * 4 + ktile) * 64 + h2 * 32 + ql) * 8 + e) * 2) =
                                f2bf(acc[mi][ni][r]);
                        }
                }
            }
        }
        __syncthreads();
        {
            const int hh = tid >> 7, t = tid & 127;
            const int hg = (bn >> 6) + hh;
            const size_t a0 = (size_t)(bb * 8 + hg) * 131072;
            const size_t slab = (Z == 0) ? a0 + (size_t)(s0 + p * 64) * 64
                                         : a0 + (size_t)((s0 >> 6) + p) * 4096;
            const char* img = SMRAW + hh * 8192;
#pragma unroll
            for (int i = 0; i < 4; ++i) {
                const int G = i * 128 + t;
                bf16x8 vv = *(const bf16x8*)(img + G * 16);
                *(bf16x8*)&Cb[slab + (size_t)G * 8] = vv;
            }
        }
        if (p == 0) __syncthreads();
    }
}

// ---------------- flash attention, swapped 32x32, QBLK=64/wave (round-13, 78us) ----------------
__global__ __launch_bounds__(256, 2)
void k_attn(const bf16* __restrict__ Qp, const bf16* __restrict__ Khp,
            const bf16* __restrict__ Vtp, bf16* __restrict__ O)
{
    __shared__ bf16 smem[16384];   // 2 bufs x (8KB K + 8KB V)
    const int tid = threadIdx.x;
    const int l   = tid & 63;
    const int w   = tid >> 6;
    const int h   = l >> 5;
    const int ql  = l & 31;
    const int d   = blockIdx.x;
    const int bh  = ((d >> 6) << 3) | (d & 7);
    const int qt  = (d >> 3) & 7;
    const size_t base = (size_t)bh * 131072;
    const int q0 = qt * 256 + w * 64;
    const int loff = l * 16;

    bf16x8 qfA[4], qfB[4];
#pragma unroll
    for (int ks = 0; ks < 4; ++ks) {
        qfA[ks] = *(const bf16x8*)&Qp[base + (size_t)(q0 + ql) * 64 + ks * 16 + h * 8];
        qfB[ks] = *(const bf16x8*)&Qp[base + (size_t)(q0 + 32 + ql) * 64 + ks * 16 + h * 8];
    }

    f32x16 oA0 = {}, oA1 = {}, oB0 = {}, oB1 = {};
    float lrunA = 0.f, lrunB = 0.f;

    const bf16* ksrc = Khp + base + tid * 8;
    const bf16* vsrc = Vtp + base + tid * 8;
    char* kb0 = (char*)smem;
    char* kb1 = (char*)smem + 16384;
    const int wdst = w * 1024;

    auto stage = [&](int kvt, char* kb) {
        const bf16* ks = ksrc + kvt * 4096;
        const bf16* vs = vsrc + kvt * 4096;
        gll16(ks,        kb + wdst);
        gll16(ks + 2048, kb + 4096 + wdst);
        gll16(vs,        kb + 8192 + wdst);
        gll16(vs + 2048, kb + 12288 + wdst);
    };

    auto compute = [&](const char* kb) {
        f32x16 sA0 = {}, sA1 = {}, sB0 = {}, sB1 = {};
        __builtin_amdgcn_s_setprio(1);
#pragma unroll
        for (int ks = 0; ks < 4; ++ks) {
            bf16x8 a0 = *(const bf16x8*)(kb + ks * 1024 + loff);
            bf16x8 a1 = *(const bf16x8*)(kb + 4096 + ks * 1024 + loff);
            sA0 = __builtin_amdgcn_mfma_f32_32x32x16_bf16(a0, qfA[ks], sA0, 0, 0, 0);
            sB0 = __builtin_amdgcn_mfma_f32_32x32x16_bf16(a0, qfB[ks], sB0, 0, 0, 0);
            sA1 = __builtin_amdgcn_mfma_f32_32x32x16_bf16(a1, qfA[ks], sA1, 0, 0, 0);
            sB1 = __builtin_amdgcn_mfma_f32_32x32x16_bf16(a1, qfB[ks], sB1, 0, 0, 0);
        }
        __builtin_amdgcn_s_setprio(0);

        f32x2 pA = {0.f, 0.f}, pB = {0.f, 0.f};
#pragma unroll
        for (int r = 0; r < 16; r += 2) {
            sA0[r]     = fexp2(sA0[r]);
            sA0[r + 1] = fexp2(sA0[r + 1]);
            sA1[r]     = fexp2(sA1[r]);
            sA1[r + 1] = fexp2(sA1[r + 1]);
            pA += (f32x2){sA0[r], sA0[r + 1]};
            pA += (f32x2){sA1[r], sA1[r + 1]};
        }
#pragma unroll
        for (int r = 0; r < 16; r += 2) {
            sB0[r]     = fexp2(sB0[r]);
            sB0[r + 1] = fexp2(sB0[r + 1]);
            sB1[r]     = fexp2(sB1[r]);
            sB1[r + 1] = fexp2(sB1[r + 1]);
            pB += (f32x2){sB0[r], sB0[r + 1]};
            pB += (f32x2){sB1[r], sB1[r + 1]};
        }
        lrunA += pA[0] + pA[1];
        lrunB += pB[0] + pB[1];

        bf16x8 pbA[4], pbB[4];
#pragma unroll
        for (int j = 0; j < 4; ++j) {
            const int ofs = 8 * (j & 1);
#pragma unroll
            for (int e = 0; e < 8; ++e) {
                pbA[j][e] = f2bf((j & 2) ? sA1[ofs + e] : sA0[ofs + e]);
                pbB[j][e] = f2bf((j & 2) ? sB1[ofs + e] : sB0[ofs + e]);
            }
        }

        const char* vr = kb + 8192;
        __builtin_amdgcn_s_setprio(1);
#pragma unroll
        for (int j = 0; j < 4; ++j) {
            bf16x8 a0 = *(const bf16x8*)(vr + j * 1024 + loff);
            bf16x8 a1 = *(const bf16x8*)(vr + 4096 + j * 1024 + loff);
            oA0 = __builtin_amdgcn_mfma_f32_32x32x16_bf16(a0, pbA[j], oA0, 0, 0, 0);
            oB0 = __builtin_amdgcn_mfma_f32_32x32x16_bf16(a0, pbB[j], oB0, 0, 0, 0);
            oA1 = __builtin_amdgcn_mfma_f32_32x32x16_bf16(a1, pbA[j], oA1, 0, 0, 0);
            oB1 = __builtin_amdgcn_mfma_f32_32x32x16_bf16(a1, pbB[j], oB1, 0, 0, 0);
        }
        __builtin_amdgcn_s_setprio(0);
    };

    stage(0, kb0);
    __syncthreads();
    for (int kvt = 0; kvt < 32; kvt += 2) {
        if (kvt + 1 < 32) stage(kvt + 1, kb1);
        compute(kb0);
        __syncthreads();
        if (kvt + 2 < 32) stage(kvt + 2, kb0);
        compute(kb1);
        __syncthreads();
    }

    char* ot = (char*)smem + w * 4096;
    const int qr = l >> 1;
    const int dh4 = (l & 1) * 4;
    auto epi = [&](const f32x16& e0, const f32x16& e1, float lr, int qg) {
        lr += __shfl_xor(lr, 32);
        const float inv = 1.f / lr;
#pragma unroll
        for (int dvt = 0; dvt < 2; ++dvt) {
#pragma unroll
            for (int r = 0; r < 16; ++r) {
                const int dv = dvt * 32 + (r & 3) + 8 * (r >> 2) + 4 * h;
                const float val = (dvt ? e1[r] : e0[r]) * inv;
                *(bf16*)(ot + ql * 128 + ((((dv >> 3) ^ (ql & 7)) << 4) | ((dv & 7) << 1))) = f2bf(val);
            }
        }
        const size_t ob = ((size_t)(bh >> 3) * 2048 + qg + qr) * 512 + (bh & 7) * 64 + (size_t)dh4 * 8;
#pragma unroll
        for (int B = 0; B < 4; ++B) {
            bf16x8 v = *(const bf16x8*)(ot + qr * 128 + (((dh4 + B) ^ (qr & 7)) << 4));
            *(bf16x8*)&O[ob + B * 8] = v;
        }
    };
    epi(oA0, oA1, lrunA, q0);
    epi(oB0, oB1, lrunB, q0 + 32);
}

// ---------------- launch ----------------
extern "C" void kernel_launch(void* const* d_in, const int* in_sizes, int n_in,
                              void* d_out, int out_size, void* d_ws, size_t ws_size,
                              hipStream_t stream)
{
    const float* Q  = (const float*)d_in[0];
    const float* K  = (const float*)d_in[1];
    const float* V  = (const float*)d_in[2];
    const float* Wq = (const float*)d_in[3];
    const float* Wk = (const float*)d_in[4];
    const float* Wv = (const float*)d_in[5];
    const float* Wo = (const float*)d_in[6];
    const float* W1 = (const float*)d_in[7];
    const float* b1 = (const float*)d_in[8];
    const float* W2 = (const float*)d_in[9];
    const float* b2 = (const float*)d_in[10];
    float* out = (float*)d_out;

    const int M = 8 * 2048;                 // 16384 rows
    const size_t TN = (size_t)M * 512;      // 8388608 elems
    const int WN = 512 * 512;               // 262144

    char* ws = (char*)d_ws;
    bf16* Qhp  = (bf16*)ws;  // head-split, scaled
    bf16* Khp  = Qhp + TN;   // fragment-ordered K
    bf16* Vtp  = Khp + TN;   // fragment-ordered transposed V
    bf16* Vatt = Vtp + TN;
    bf16* H1   = Vatt + TN;
    bf16* Xbf  = H1 + TN;
    bf16* Wqt  = Xbf + TN;
    bf16* Wkt  = Wqt + WN;
    bf16* Wvt  = Wkt + WN;
    bf16* Wot  = Wvt + WN;
    bf16* W1b  = Wot + WN;
    bf16* W2b  = W1b + WN;

    // weight casts (LDS tile transpose, coalesced)
    k_castw<<<dim3(64, 6), 256, 0, stream>>>(Wq, Wk, Wv, Wo, W1, W2,
                                             Wqt, Wkt, Wvt, Wot, W1b, W2b);

    // fused cast+projections, one Z per launch (separately profiled)
    k_projZ<0><<<512, 256, 0, stream>>>(Q, Wqt, Qhp);
    k_projZ<1><<<512, 256, 0, stream>>>(K, Wkt, Khp);
    k_projZ<2><<<512, 256, 0, stream>>>(V, Wvt, Vtp);

    // attention (512 blocks, 2/CU)
    k_attn<<<512, 256, 0, stream>>>(Qhp, Khp, Vtp, Vatt);

    dim3 gg(4, 128);
    // W_o + residual(Q fp32) -> Xbf
    k_gemm<1><<<gg, 256, 0, stream>>>(Vatt, Wot, nullptr, Q, nullptr, nullptr, Xbf, M, 512, 512);
    // FFN1: relu(Xbf W1^T + b1) -> H1
    k_gemm<2><<<gg, 256, 0, stream>>>(Xbf, W1b, b1, nullptr, nullptr, nullptr, H1, M, 512, 512);
    // FFN2: H1 W2^T + b2 + Xbf -> out
    k_gemm<3><<<gg, 256, 0, stream>>>(H1, W2b, b2, nullptr, Xbf, out, nullptr, M, 512, 512);
}

// Round 17
// 193.678 us; speedup vs baseline: 1.1263x; 1.0568x over previous
//
#include <hip/hip_runtime.h>
#include <stdint.h>

typedef __bf16 bf16;
typedef bf16 bf16x8 __attribute__((ext_vector_type(8)));
typedef bf16 bf16x4 __attribute__((ext_vector_type(4)));
typedef float f32x2 __attribute__((ext_vector_type(2)));
typedef float f32x4 __attribute__((ext_vector_type(4)));
typedef float f32x16 __attribute__((ext_vector_type(16)));

#define AS1 __attribute__((address_space(1)))
#define AS3 __attribute__((address_space(3)))

__device__ __forceinline__ void gll16(const void* g, void* l) {
    __builtin_amdgcn_global_load_lds((const AS1 unsigned int*)g,
                                     (AS3 unsigned int*)l, 16, 0, 0);
}

// native RTNE f32->bf16
__device__ __forceinline__ bf16 f2bf(float x) { return (bf16)x; }

// single-instruction v_exp_f32 (2^x); avoids glibc __exp2f macro collision
__device__ __forceinline__ float fexp2(float x) { return __builtin_amdgcn_exp2f(x); }

// QK scale folded into Q projection: (1/(8+1e-6)) * log2(e)
#define QSCALE_LOG2E 0.18033685757f

// ---------------- weight casts ----------------
// z = blockIdx.y: 0..3 transpose-cast Wq/Wk/Wv/Wo; 4,5 straight-cast W1,W2
__global__ void k_castw(const float* __restrict__ Wq, const float* __restrict__ Wk,
                        const float* __restrict__ Wv, const float* __restrict__ Wo,
                        const float* __restrict__ W1, const float* __restrict__ W2,
                        bf16* __restrict__ oq, bf16* __restrict__ ok, bf16* __restrict__ ov,
                        bf16* __restrict__ oo, bf16* __restrict__ o1, bf16* __restrict__ o2)
{
    const int z = blockIdx.y;
    const int idx = blockIdx.x * 256 + threadIdx.x;
    const float* src = z == 0 ? Wq : z == 1 ? Wk : z == 2 ? Wv : z == 3 ? Wo : z == 4 ? W1 : W2;
    bf16* dst = z == 0 ? oq : z == 1 ? ok : z == 2 ? ov : z == 3 ? oo : z == 4 ? o1 : o2;
    if (z < 4) {
        const int n = idx >> 9, k = idx & 511;
        dst[idx] = f2bf(src[(k << 9) + n]);
    } else {
        dst[idx] = f2bf(src[idx]);
    }
}

// ---------------- shared GEMM core (bf16 A): C[128,128] += A[M,K] * Bt[N,K]^T ----------------
__device__ __forceinline__ void gemm_core(const bf16* __restrict__ A,
                                          const bf16* __restrict__ Bt,
                                          const int K, bf16* As, bf16* Bs,
                                          const int bm, const int bn,
                                          f32x4 acc[4][4])
{
    const int tid  = threadIdx.x;
    const int lane = tid & 63;
    const int wave = tid >> 6;
    const int g    = lane >> 4;
    const int l15  = lane & 15;
    const int wm   = (wave >> 1) * 64;
    const int wn   = (wave & 1) * 64;

    const int srow = tid >> 2;
    const int sk   = (tid & 3) * 8;
    const size_t aoff0 = (size_t)(bm + srow) * K + sk;
    const size_t aoff1 = (size_t)(bm + 64 + srow) * K + sk;
    const size_t boff0 = (size_t)(bn + srow) * K + sk;
    const size_t boff1 = (size_t)(bn + 64 + srow) * K + sk;
    char* asb = (char*)As + wave * 1024;
    char* bsb = (char*)Bs + wave * 1024;

    for (int kt = 0; kt < K; kt += 32) {
        __syncthreads();
        gll16(A + aoff0 + kt, asb);
        gll16(A + aoff1 + kt, asb + 4096);
        gll16(Bt + boff0 + kt, bsb);
        gll16(Bt + boff1 + kt, bsb + 4096);
        __syncthreads();
        bf16x8 af[4], bfv[4];
#pragma unroll
        for (int mi = 0; mi < 4; ++mi)
            af[mi] = *(const bf16x8*)&As[(wm + mi * 16 + l15) * 32 + g * 8];
#pragma unroll
        for (int ni = 0; ni < 4; ++ni)
            bfv[ni] = *(const bf16x8*)&Bs[(wn + ni * 16 + l15) * 32 + g * 8];
#pragma unroll
        for (int mi = 0; mi < 4; ++mi)
#pragma unroll
            for (int ni = 0; ni < 4; ++ni)
                acc[mi][ni] = __builtin_amdgcn_mfma_f32_16x16x32_bf16(
                    af[mi], bfv[ni], acc[mi][ni], 0, 0, 0);
    }
}

// ---------------- generic epilogue GEMMs ----------------
// EPI 1: Cb = bf16(acc + residf)                  (W_o + fp32 Q residual -> Xbf)
// EPI 2: Cb = bf16(relu(acc + bias[col]))         (FFN1 -> H1)
// EPI 3: Cf = acc + bias[col] + float(residb)     (FFN2 + residual -> out)
template<int EPI>
__global__ __launch_bounds__(256)
void k_gemm(const bf16* __restrict__ A, const bf16* __restrict__ Bt,
            const float* __restrict__ bias, const float* __restrict__ residf,
            const bf16* __restrict__ residb,
            float* __restrict__ Cf, bf16* __restrict__ Cb,
            int M, int N, int K)
{
    __shared__ bf16 As[128 * 32];
    __shared__ bf16 Bs[128 * 32];
    const int bm = blockIdx.y * 128, bn = blockIdx.x * 128;
    f32x4 acc[4][4] = {};
    gemm_core(A, Bt, K, As, Bs, bm, bn, acc);

    const int tid  = threadIdx.x;
    const int lane = tid & 63;
    const int wave = tid >> 6;
    const int g    = lane >> 4;
    const int l15  = lane & 15;
    const int wm   = (wave >> 1) * 64;
    const int wn   = (wave & 1) * 64;
    const int col0 = bn + wn + l15;
#pragma unroll
    for (int ni = 0; ni < 4; ++ni) {
        const int col = col0 + ni * 16;
        float bv = 0.f;
        if constexpr (EPI == 2 || EPI == 3) bv = bias[col];
#pragma unroll
        for (int mi = 0; mi < 4; ++mi) {
#pragma unroll
            for (int r = 0; r < 4; ++r) {
                const int row = bm + wm + mi * 16 + 4 * g + r;
                const size_t idx = (size_t)row * N + col;
                float v = acc[mi][ni][r];
                if constexpr (EPI == 1) {
                    Cb[idx] = f2bf(v + residf[idx]);
                } else if constexpr (EPI == 2) {
                    Cb[idx] = f2bf(fmaxf(v + bv, 0.f));
                } else {
                    Cf[idx] = v + bv + (float)residb[idx];
                }
            }
        }
    }
}

// ---------------- fused cast+projection, k_gemm structure ----------------
// 128x128 tile, 256 threads, single-buffer 2-barrier loop (k_gemm's proven shape).
// A kept fp32 through LDS (16KB tile) via gll16 with SOURCE-pre-swizzled 16B chunks
// (kc ^= row&7 within each 128B row; coalescing preserved); fragments read as 2x
// float4 at swizzled positions (conflict-free) + cvt at use. B staged as k_gemm.
// XCD-grouped linear grid: the 4 bn-blocks sharing an A-panel are consecutive in
// one XCD's dispatch stream -> panel (256KB) served from that XCD's L2.
// Epilogue: LDS-image scatter + contiguous copy-out (image reuses A region).
// z: 0=Q (scaled, row-major head-split), 1=K frag-ordered, 2=V frag-ordered.
__global__ __launch_bounds__(256)
void k_proj(const float* __restrict__ Qf, const float* __restrict__ Kf, const float* __restrict__ Vf,
            const bf16* __restrict__ BQ, const bf16* __restrict__ BK, const bf16* __restrict__ BV,
            bf16* __restrict__ OQ, bf16* __restrict__ OK_, bf16* __restrict__ OV)
{
    __shared__ char SMRAW[24576];        // 16KB fp32 A + 8KB bf16 B; image reuses A
    bf16* Bs = (bf16*)(SMRAW + 16384);

    // XCD-grouped decode: x = XCD slot, 4 bn-blocks of one (z,bm) adjacent per XCD
    const int dd = blockIdx.x;
    const int x = dd & 7, q = dd >> 3;
    const int bnb = q & 3;
    const int tt = x * 48 + (q >> 2);    // 0..383
    const int z  = tt >> 7;
    const int bm = (tt & 127) * 128;
    const int bn = bnb * 128;

    const float* A = z == 0 ? Qf : z == 1 ? Kf : Vf;
    const bf16* Bt = z == 0 ? BQ : z == 1 ? BK : BV;
    bf16* Cb       = z == 0 ? OQ : z == 1 ? OK_ : OV;

    const int tid  = threadIdx.x;
    const int lane = tid & 63;
    const int wave = tid >> 6;
    const int g    = lane >> 4;
    const int l15  = lane & 15;
    const int wm   = (wave >> 1) * 64;
    const int wn   = (wave & 1) * 64;

    // ---- A staging: issue j covers rows j*32..j*32+31; thread -> row j*32+(tid>>3),
    //      16B chunk kc = tid&7, source-swizzled kc^(row&7)
    const int krow = tid >> 3, kc = tid & 7;
    const size_t aoff = (size_t)(bm + krow) * 512 + ((kc ^ (krow & 7)) << 2);
    // ---- B staging: k_gemm pattern
    const int srow = tid >> 2;
    const int sk   = (tid & 3) * 8;
    const size_t boff0 = (size_t)(bn + srow) * 512 + sk;
    const size_t boff1 = (size_t)(bn + 64 + srow) * 512 + sk;
    char* bsb = (char*)Bs + wave * 1024;

    f32x4 acc[4][4] = {};

    for (int kt = 0; kt < 512; kt += 32) {
        __syncthreads();
#pragma unroll
        for (int j = 0; j < 4; ++j)
            gll16(A + aoff + j * 16384 + kt, SMRAW + j * 4096 + tid * 16);
        gll16(Bt + boff0 + kt, bsb);
        gll16(Bt + boff1 + kt, bsb + 4096);
        __syncthreads();
        bf16x8 af[4];
        bf16x8 bfv[4];
#pragma unroll
        for (int mi = 0; mi < 4; ++mi) {
            const int row = wm + mi * 16 + l15;
            const int r7 = row & 7;
            float4 lo = *(const float4*)(SMRAW + row * 128 + (((2 * g) ^ r7) << 4));
            float4 hi = *(const float4*)(SMRAW + row * 128 + (((2 * g + 1) ^ r7) << 4));
            af[mi][0] = f2bf(lo.x); af[mi][1] = f2bf(lo.y);
            af[mi][2] = f2bf(lo.z); af[mi][3] = f2bf(lo.w);
            af[mi][4] = f2bf(hi.x); af[mi][5] = f2bf(hi.y);
            af[mi][6] = f2bf(hi.z); af[mi][7] = f2bf(hi.w);
        }
#pragma unroll
        for (int ni = 0; ni < 4; ++ni)
            bfv[ni] = *(const bf16x8*)&Bs[(wn + ni * 16 + l15) * 32 + g * 8];
#pragma unroll
        for (int mi = 0; mi < 4; ++mi)
#pragma unroll
            for (int ni = 0; ni < 4; ++ni)
                acc[mi][ni] = __builtin_amdgcn_mfma_f32_16x16x32_bf16(
                    af[mi], bfv[ni], acc[mi][ni], 0, 0, 0);
    }

    // ---- epilogue: LDS-image scatter + contiguous copy-out (proven round-7 form) ----
    const int bb = bm >> 11;         // batch
    const int s0 = bm & 2047;        // 128-aligned sequence base
    __syncthreads();                 // protect A region before reuse as image
#pragma unroll
    for (int p = 0; p < 2; ++p) {
        if ((wave >> 1) == p) {
            if (z == 0) {
#pragma unroll
                for (int ni = 0; ni < 4; ++ni) {
                    const int col = wn + ni * 16 + l15;   // block-local column
                    const int hh = col >> 6, dk = col & 63;
                    char* img = SMRAW + hh * 8192;
#pragma unroll
                    for (int mi = 0; mi < 4; ++mi)
#pragma unroll
                        for (int r = 0; r < 4; ++r) {
                            const int sl = mi * 16 + 4 * g + r;
                            *(bf16*)(img + (sl * 64 + dk) * 2) =
                                f2bf(acc[mi][ni][r] * QSCALE_LOG2E);
                        }
                }
            } else if (z == 1) {
#pragma unroll
                for (int ni = 0; ni < 4; ++ni) {
                    const int col = wn + ni * 16 + l15;
                    const int hh = col >> 6, dk = col & 63;
                    const int ks = dk >> 4, h2 = (dk >> 3) & 1, e = dk & 7;
                    char* img = SMRAW + hh * 8192;
#pragma unroll
                    for (int mi = 0; mi < 4; ++mi)
#pragma unroll
                        for (int r = 0; r < 4; ++r) {
                            const int sl = mi * 16 + 4 * g + r;
                            const int t2 = sl >> 5, ql = sl & 31;
                            *(bf16*)(img + (((t2 * 4 + ks) * 64 + h2 * 32 + ql) * 8 + e) * 2) =
                                f2bf(acc[mi][ni][r]);
                        }
                }
            } else {
#pragma unroll
                for (int ni = 0; ni < 4; ++ni) {
                    const int col = wn + ni * 16 + l15;
                    const int hh = col >> 6, dv = col & 63;
                    const int dvt = dv >> 5, ql = dv & 31;
                    char* img = SMRAW + hh * 8192;
#pragma unroll
                    for (int mi = 0; mi < 4; ++mi)
#pragma unroll
                        for (int r = 0; r < 4; ++r) {
                            const int sl = mi * 16 + 4 * g + r;
                            const int ktile = sl >> 4, kk = sl & 15;
                            const int h2 = (kk >> 2) & 1;
                            const int e = (kk & 3) | ((kk >> 3) << 2);
                            *(bf16*)(img + (((dvt * 4 + ktile) * 64 + h2 * 32 + ql) * 8 + e) * 2) =
                                f2bf(acc[mi][ni][r]);
                        }
                }
            }
        }
        __syncthreads();
        {   // linear copy-out: 256 threads x 4 x (b128 read + 16B store)
            const int hh = tid >> 7, t = tid & 127;
            const int hg = (bn >> 6) + hh;              // GLOBAL head index
            const size_t a0 = (size_t)(bb * 8 + hg) * 131072;
            const size_t slab = (z == 0) ? a0 + (size_t)(s0 + p * 64) * 64
                                         : a0 + (size_t)((s0 >> 6) + p) * 4096;
            const char* img = SMRAW + hh * 8192;
#pragma unroll
            for (int i = 0; i < 4; ++i) {
                const int G = i * 128 + t;
                bf16x8 vv = *(const bf16x8*)(img + G * 16);
                *(bf16x8*)&Cb[slab + (size_t)G * 8] = vv;
            }
        }
        if (p == 0) __syncthreads();
    }
}

// ---------------- flash attention, swapped 32x32, QBLK=64/wave ----------------
__global__ __launch_bounds__(256, 2)
void k_attn(const bf16* __restrict__ Qp, const bf16* __restrict__ Khp,
            const bf16* __restrict__ Vtp, bf16* __restrict__ O)
{
    __shared__ bf16 smem[16384];   // 2 bufs x (8KB K + 8KB V)
    const int tid = threadIdx.x;
    const int l   = tid & 63;
    const int w   = tid >> 6;
    const int h   = l >> 5;
    const int ql  = l & 31;
    // XCD-chunked swizzle: xcd = d&7; 8 bh per XCD (K+V = 4MB, L2-resident)
    const int d   = blockIdx.x;
    const int bh  = ((d >> 6) << 3) | (d & 7);
    const int qt  = (d >> 3) & 7;
    const size_t base = (size_t)bh * 131072;
    const int q0 = qt * 256 + w * 64;
    const int loff = l * 16;

    // Q fragments (B-operand), two 32-row groups
    bf16x8 qfA[4], qfB[4];
#pragma unroll
    for (int ks = 0; ks < 4; ++ks) {
        qfA[ks] = *(const bf16x8*)&Qp[base + (size_t)(q0 + ql) * 64 + ks * 16 + h * 8];
        qfB[ks] = *(const bf16x8*)&Qp[base + (size_t)(q0 + 32 + ql) * 64 + ks * 16 + h * 8];
    }

    f32x16 oA0 = {}, oA1 = {}, oB0 = {}, oB1 = {};
    float lrunA = 0.f, lrunB = 0.f;

    const bf16* ksrc = Khp + base + tid * 8;
    const bf16* vsrc = Vtp + base + tid * 8;
    char* kb0 = (char*)smem;
    char* kb1 = (char*)smem + 16384;
    const int wdst = w * 1024;

    auto stage = [&](int kvt, char* kb) {
        const bf16* ks = ksrc + kvt * 4096;
        const bf16* vs = vsrc + kvt * 4096;
        gll16(ks,        kb + wdst);
        gll16(ks + 2048, kb + 4096 + wdst);
        gll16(vs,        kb + 8192 + wdst);
        gll16(vs + 2048, kb + 12288 + wdst);
    };

    auto compute = [&](const char* kb) {
        // ---- S^T = K Q^T : each A-fragment read feeds both q-groups ----
        f32x16 sA0 = {}, sA1 = {}, sB0 = {}, sB1 = {};
        __builtin_amdgcn_s_setprio(1);
#pragma unroll
        for (int ks = 0; ks < 4; ++ks) {
            bf16x8 a0 = *(const bf16x8*)(kb + ks * 1024 + loff);
            bf16x8 a1 = *(const bf16x8*)(kb + 4096 + ks * 1024 + loff);
            sA0 = __builtin_amdgcn_mfma_f32_32x32x16_bf16(a0, qfA[ks], sA0, 0, 0, 0);
            sB0 = __builtin_amdgcn_mfma_f32_32x32x16_bf16(a0, qfB[ks], sB0, 0, 0, 0);
            sA1 = __builtin_amdgcn_mfma_f32_32x32x16_bf16(a1, qfA[ks], sA1, 0, 0, 0);
            sB1 = __builtin_amdgcn_mfma_f32_32x32x16_bf16(a1, qfB[ks], sB1, 0, 0, 0);
        }
        __builtin_amdgcn_s_setprio(0);

        // ---- exp2 (native v_exp_f32) + packed lane-local partial sums ----
        f32x2 pA = {0.f, 0.f}, pB = {0.f, 0.f};
#pragma unroll
        for (int r = 0; r < 16; r += 2) {
            sA0[r]     = fexp2(sA0[r]);
            sA0[r + 1] = fexp2(sA0[r + 1]);
            sA1[r]     = fexp2(sA1[r]);
            sA1[r + 1] = fexp2(sA1[r + 1]);
            pA += (f32x2){sA0[r], sA0[r + 1]};
            pA += (f32x2){sA1[r], sA1[r + 1]};
        }
#pragma unroll
        for (int r = 0; r < 16; r += 2) {
            sB0[r]     = fexp2(sB0[r]);
            sB0[r + 1] = fexp2(sB0[r + 1]);
            sB1[r]     = fexp2(sB1[r]);
            sB1[r + 1] = fexp2(sB1[r + 1]);
            pB += (f32x2){sB0[r], sB0[r + 1]};
            pB += (f32x2){sB1[r], sB1[r + 1]};
        }
        lrunA += pA[0] + pA[1];
        lrunB += pB[0] + pB[1];

        // ---- P fragments (C/D order -> B operand) ----
        bf16x8 pbA[4], pbB[4];
#pragma unroll
        for (int j = 0; j < 4; ++j) {
            const int ofs = 8 * (j & 1);
#pragma unroll
            for (int e = 0; e < 8; ++e) {
                pbA[j][e] = f2bf((j & 2) ? sA1[ofs + e] : sA0[ofs + e]);
                pbB[j][e] = f2bf((j & 2) ? sB1[ofs + e] : sB0[ofs + e]);
            }
        }

        // ---- O^T += V^T P : each V-fragment read feeds both q-groups ----
        const char* vr = kb + 8192;
        __builtin_amdgcn_s_setprio(1);
#pragma unroll
        for (int j = 0; j < 4; ++j) {
            bf16x8 a0 = *(const bf16x8*)(vr + j * 1024 + loff);
            bf16x8 a1 = *(const bf16x8*)(vr + 4096 + j * 1024 + loff);
            oA0 = __builtin_amdgcn_mfma_f32_32x32x16_bf16(a0, pbA[j], oA0, 0, 0, 0);
            oB0 = __builtin_amdgcn_mfma_f32_32x32x16_bf16(a0, pbB[j], oB0, 0, 0, 0);
            oA1 = __builtin_amdgcn_mfma_f32_32x32x16_bf16(a1, pbA[j], oA1, 0, 0, 0);
            oB1 = __builtin_amdgcn_mfma_f32_32x32x16_bf16(a1, pbB[j], oB1, 0, 0, 0);
        }
        __builtin_amdgcn_s_setprio(0);
    };

    stage(0, kb0);
    __syncthreads();
    for (int kvt = 0; kvt < 32; kvt += 2) {
        if (kvt + 1 < 32) stage(kvt + 1, kb1);
        compute(kb0);
        __syncthreads();
        if (kvt + 2 < 32) stage(kvt + 2, kb0);
        compute(kb1);
        __syncthreads();
    }

    // ---- epilogue per q-group: normalize, transpose via per-wave LDS, store ----
    char* ot = (char*)smem + w * 4096;
    const int qr = l >> 1;
    const int dh4 = (l & 1) * 4;
    auto epi = [&](const f32x16& e0, const f32x16& e1, float lr, int qg) {
        lr += __shfl_xor(lr, 32);
        const float inv = 1.f / lr;
#pragma unroll
        for (int dvt = 0; dvt < 2; ++dvt) {
#pragma unroll
            for (int r = 0; r < 16; ++r) {
                const int dv = dvt * 32 + (r & 3) + 8 * (r >> 2) + 4 * h;
                const float val = (dvt ? e1[r] : e0[r]) * inv;
                *(bf16*)(ot + ql * 128 + ((((dv >> 3) ^ (ql & 7)) << 4) | ((dv & 7) << 1))) = f2bf(val);
            }
        }
        const size_t ob = ((size_t)(bh >> 3) * 2048 + qg + qr) * 512 + (bh & 7) * 64 + (size_t)dh4 * 8;
#pragma unroll
        for (int B = 0; B < 4; ++B) {
            bf16x8 v = *(const bf16x8*)(ot + qr * 128 + (((dh4 + B) ^ (qr & 7)) << 4));
            *(bf16x8*)&O[ob + B * 8] = v;
        }
    };
    epi(oA0, oA1, lrunA, q0);
    epi(oB0, oB1, lrunB, q0 + 32);
}

// ---------------- launch ----------------
extern "C" void kernel_launch(void* const* d_in, const int* in_sizes, int n_in,
                              void* d_out, int out_size, void* d_ws, size_t ws_size,
                              hipStream_t stream)
{
    const float* Q  = (const float*)d_in[0];
    const float* K  = (const float*)d_in[1];
    const float* V  = (const float*)d_in[2];
    const float* Wq = (const float*)d_in[3];
    const float* Wk = (const float*)d_in[4];
    const float* Wv = (const float*)d_in[5];
    const float* Wo = (const float*)d_in[6];
    const float* W1 = (const float*)d_in[7];
    const float* b1 = (const float*)d_in[8];
    const float* W2 = (const float*)d_in[9];
    const float* b2 = (const float*)d_in[10];
    float* out = (float*)d_out;

    const int M = 8 * 2048;                 // 16384 rows
    const size_t TN = (size_t)M * 512;      // 8388608 elems
    const int WN = 512 * 512;               // 262144

    char* ws = (char*)d_ws;
    bf16* Qhp  = (bf16*)ws;  // head-split, scaled
    bf16* Khp  = Qhp + TN;   // fragment-ordered K
    bf16* Vtp  = Khp + TN;   // fragment-ordered transposed V
    bf16* Vatt = Vtp + TN;
    bf16* H1   = Vatt + TN;
    bf16* Xbf  = H1 + TN;
    bf16* Wqt  = Xbf + TN;
    bf16* Wkt  = Wqt + WN;
    bf16* Wvt  = Wkt + WN;
    bf16* Wot  = Wvt + WN;
    bf16* W1b  = Wot + WN;
    bf16* W2b  = W1b + WN;

    // weight casts
    k_castw<<<dim3(1024, 6), 256, 0, stream>>>(Wq, Wk, Wv, Wo, W1, W2,
                                               Wqt, Wkt, Wvt, Wot, W1b, W2b);

    // fused cast+projections, k_gemm-structure, XCD-grouped (1536 blocks)
    k_proj<<<1536, 256, 0, stream>>>(Q, K, V, Wqt, Wkt, Wvt,
                                     Qhp, Khp, Vtp);

    // attention (512 blocks, 2/CU)
    k_attn<<<512, 256, 0, stream>>>(Qhp, Khp, Vtp, Vatt);

    dim3 gg(4, 128);
    // W_o + residual(Q fp32) -> Xbf
    k_gemm<1><<<gg, 256, 0, stream>>>(Vatt, Wot, nullptr, Q, nullptr, nullptr, Xbf, M, 512, 512);
    // FFN1: relu(Xbf W1^T + b1) -> H1
    k_gemm<2><<<gg, 256, 0, stream>>>(Xbf, W1b, b1, nullptr, nullptr, nullptr, H1, M, 512, 512);
    // FFN2: H1 W2^T + b2 + Xbf -> out
    k_gemm<3><<<gg, 256, 0, stream>>>(H1, W2b, b2, nullptr, Xbf, out, nullptr, M, 512, 512);
}

// Round 18
// 188.139 us; speedup vs baseline: 1.1594x; 1.0294x over previous
//
#include <hip/hip_runtime.h>
#include <stdint.h>

typedef __bf16 bf16;
typedef bf16 bf16x8 __attribute__((ext_vector_type(8)));
typedef bf16 bf16x4 __attribute__((ext_vector_type(4)));
typedef float f32x2 __attribute__((ext_vector_type(2)));
typedef float f32x4 __attribute__((ext_vector_type(4)));
typedef float f32x16 __attribute__((ext_vector_type(16)));

#define AS1 __attribute__((address_space(1)))
#define AS3 __attribute__((address_space(3)))

__device__ __forceinline__ void gll16(const void* g, void* l) {
    __builtin_amdgcn_global_load_lds((const AS1 unsigned int*)g,
                                     (AS3 unsigned int*)l, 16, 0, 0);
}

// native RTNE f32->bf16
__device__ __forceinline__ bf16 f2bf(float x) { return (bf16)x; }

// single-instruction v_exp_f32 (2^x); avoids glibc __exp2f macro collision
__device__ __forceinline__ float fexp2(float x) { return __builtin_amdgcn_exp2f(x); }

// QK scale folded into Q projection: (1/(8+1e-6)) * log2(e)
#define QSCALE_LOG2E 0.18033685757f

// ---------------- weight casts ----------------
// z<4: transpose-cast via LDS 64x64 tile (coalesced both sides); z>=4: straight copy
__global__ void k_castw(const float* __restrict__ Wq, const float* __restrict__ Wk,
                        const float* __restrict__ Wv, const float* __restrict__ Wo,
                        const float* __restrict__ W1, const float* __restrict__ W2,
                        bf16* __restrict__ oq, bf16* __restrict__ ok, bf16* __restrict__ ov,
                        bf16* __restrict__ oo, bf16* __restrict__ o1, bf16* __restrict__ o2)
{
    __shared__ bf16 L[64][65];
    const int z = blockIdx.y;
    const int t = threadIdx.x;
    const float* src = z == 0 ? Wq : z == 1 ? Wk : z == 2 ? Wv : z == 3 ? Wo : z == 4 ? W1 : W2;
    bf16* dst = z == 0 ? oq : z == 1 ? ok : z == 2 ? ov : z == 3 ? oo : z == 4 ? o1 : o2;
    if (z < 4) {
        const int tr = blockIdx.x >> 3, tc = blockIdx.x & 7;   // 64x64 tile
        const int r = t >> 2, c0 = (t & 3) * 16;
#pragma unroll
        for (int i = 0; i < 4; ++i) {
            float4 v = *(const float4*)(src + (size_t)(tr * 64 + r) * 512 + tc * 64 + c0 + i * 4);
            L[r][c0 + i * 4 + 0] = f2bf(v.x);
            L[r][c0 + i * 4 + 1] = f2bf(v.y);
            L[r][c0 + i * 4 + 2] = f2bf(v.z);
            L[r][c0 + i * 4 + 3] = f2bf(v.w);
        }
        __syncthreads();
        const int c2 = t >> 2, r0 = (t & 3) * 16;
        bf16* d = dst + (size_t)(tc * 64 + c2) * 512 + tr * 64 + r0;
#pragma unroll
        for (int i = 0; i < 16; ++i) d[i] = L[r0 + i][c2];
    } else {
        const size_t base = (size_t)blockIdx.x * 4096 + t * 16;
#pragma unroll
        for (int i = 0; i < 4; ++i) {
            float4 v = *(const float4*)(src + base + i * 4);
            bf16x4 o;
            o[0] = f2bf(v.x); o[1] = f2bf(v.y); o[2] = f2bf(v.z); o[3] = f2bf(v.w);
            *(bf16x4*)(dst + base + i * 4) = o;
        }
    }
}

// ---------------- shared GEMM core (bf16 A): C[128,128] += A[M,K] * Bt[N,K]^T ----------------
__device__ __forceinline__ void gemm_core(const bf16* __restrict__ A,
                                          const bf16* __restrict__ Bt,
                                          const int K, bf16* As, bf16* Bs,
                                          const int bm, const int bn,
                                          f32x4 acc[4][4])
{
    const int tid  = threadIdx.x;
    const int lane = tid & 63;
    const int wave = tid >> 6;
    const int g    = lane >> 4;
    const int l15  = lane & 15;
    const int wm   = (wave >> 1) * 64;
    const int wn   = (wave & 1) * 64;

    const int srow = tid >> 2;
    const int sk   = (tid & 3) * 8;
    const size_t aoff0 = (size_t)(bm + srow) * K + sk;
    const size_t aoff1 = (size_t)(bm + 64 + srow) * K + sk;
    const size_t boff0 = (size_t)(bn + srow) * K + sk;
    const size_t boff1 = (size_t)(bn + 64 + srow) * K + sk;
    char* asb = (char*)As + wave * 1024;
    char* bsb = (char*)Bs + wave * 1024;

    for (int kt = 0; kt < K; kt += 32) {
        __syncthreads();
        gll16(A + aoff0 + kt, asb);
        gll16(A + aoff1 + kt, asb + 4096);
        gll16(Bt + boff0 + kt, bsb);
        gll16(Bt + boff1 + kt, bsb + 4096);
        __syncthreads();
        bf16x8 af[4], bfv[4];
#pragma unroll
        for (int mi = 0; mi < 4; ++mi)
            af[mi] = *(const bf16x8*)&As[(wm + mi * 16 + l15) * 32 + g * 8];
#pragma unroll
        for (int ni = 0; ni < 4; ++ni)
            bfv[ni] = *(const bf16x8*)&Bs[(wn + ni * 16 + l15) * 32 + g * 8];
#pragma unroll
        for (int mi = 0; mi < 4; ++mi)
#pragma unroll
            for (int ni = 0; ni < 4; ++ni)
                acc[mi][ni] = __builtin_amdgcn_mfma_f32_16x16x32_bf16(
                    af[mi], bfv[ni], acc[mi][ni], 0, 0, 0);
    }
}

// ---------------- generic epilogue GEMMs ----------------
// EPI 1: Cb = bf16(acc + residf)                  (W_o + fp32 Q residual -> Xbf)
// EPI 2: Cb = bf16(relu(acc + bias[col]))         (FFN1 -> H1)
// EPI 3: Cf = acc + bias[col] + float(residb)     (FFN2 + residual -> out)
template<int EPI>
__global__ __launch_bounds__(256)
void k_gemm(const bf16* __restrict__ A, const bf16* __restrict__ Bt,
            const float* __restrict__ bias, const float* __restrict__ residf,
            const bf16* __restrict__ residb,
            float* __restrict__ Cf, bf16* __restrict__ Cb,
            int M, int N, int K)
{
    __shared__ bf16 As[128 * 32];
    __shared__ bf16 Bs[128 * 32];
    const int bm = blockIdx.y * 128, bn = blockIdx.x * 128;
    f32x4 acc[4][4] = {};
    gemm_core(A, Bt, K, As, Bs, bm, bn, acc);

    const int tid  = threadIdx.x;
    const int lane = tid & 63;
    const int wave = tid >> 6;
    const int g    = lane >> 4;
    const int l15  = lane & 15;
    const int wm   = (wave >> 1) * 64;
    const int wn   = (wave & 1) * 64;
    const int col0 = bn + wn + l15;
#pragma unroll
    for (int ni = 0; ni < 4; ++ni) {
        const int col = col0 + ni * 16;
        float bv = 0.f;
        if constexpr (EPI == 2 || EPI == 3) bv = bias[col];
#pragma unroll
        for (int mi = 0; mi < 4; ++mi) {
#pragma unroll
            for (int r = 0; r < 4; ++r) {
                const int row = bm + wm + mi * 16 + 4 * g + r;
                const size_t idx = (size_t)row * N + col;
                float v = acc[mi][ni][r];
                if constexpr (EPI == 1) {
                    Cb[idx] = f2bf(v + residf[idx]);
                } else if constexpr (EPI == 2) {
                    Cb[idx] = f2bf(fmaxf(v + bv, 0.f));
                } else {
                    Cf[idx] = v + bv + (float)residb[idx];
                }
            }
        }
    }
}

// ---------------- fused cast+projection, k_gemm structure (round-13, proven) ----------------
__global__ __launch_bounds__(256)
void k_proj(const float* __restrict__ Qf, const float* __restrict__ Kf, const float* __restrict__ Vf,
            const bf16* __restrict__ BQ, const bf16* __restrict__ BK, const bf16* __restrict__ BV,
            bf16* __restrict__ OQ, bf16* __restrict__ OK_, bf16* __restrict__ OV)
{
    __shared__ char SMRAW[24576];        // 16KB fp32 A + 8KB bf16 B; image reuses A
    bf16* Bs = (bf16*)(SMRAW + 16384);

    // XCD-grouped decode: x = XCD slot, 4 bn-blocks of one (z,bm) adjacent per XCD
    const int dd = blockIdx.x;
    const int x = dd & 7, q = dd >> 3;
    const int bnb = q & 3;
    const int tt = x * 48 + (q >> 2);    // 0..383
    const int z  = tt >> 7;
    const int bm = (tt & 127) * 128;
    const int bn = bnb * 128;

    const float* A = z == 0 ? Qf : z == 1 ? Kf : Vf;
    const bf16* Bt = z == 0 ? BQ : z == 1 ? BK : BV;
    bf16* Cb       = z == 0 ? OQ : z == 1 ? OK_ : OV;

    const int tid  = threadIdx.x;
    const int lane = tid & 63;
    const int wave = tid >> 6;
    const int g    = lane >> 4;
    const int l15  = lane & 15;
    const int wm   = (wave >> 1) * 64;
    const int wn   = (wave & 1) * 64;

    const int krow = tid >> 3, kc = tid & 7;
    const size_t aoff = (size_t)(bm + krow) * 512 + ((kc ^ (krow & 7)) << 2);
    const int srow = tid >> 2;
    const int sk   = (tid & 3) * 8;
    const size_t boff0 = (size_t)(bn + srow) * 512 + sk;
    const size_t boff1 = (size_t)(bn + 64 + srow) * 512 + sk;
    char* bsb = (char*)Bs + wave * 1024;

    f32x4 acc[4][4] = {};

    for (int kt = 0; kt < 512; kt += 32) {
        __syncthreads();
#pragma unroll
        for (int j = 0; j < 4; ++j)
            gll16(A + aoff + j * 16384 + kt, SMRAW + j * 4096 + tid * 16);
        gll16(Bt + boff0 + kt, bsb);
        gll16(Bt + boff1 + kt, bsb + 4096);
        __syncthreads();
        bf16x8 af[4];
        bf16x8 bfv[4];
#pragma unroll
        for (int mi = 0; mi < 4; ++mi) {
            const int row = wm + mi * 16 + l15;
            const int r7 = row & 7;
            float4 lo = *(const float4*)(SMRAW + row * 128 + (((2 * g) ^ r7) << 4));
            float4 hi = *(const float4*)(SMRAW + row * 128 + (((2 * g + 1) ^ r7) << 4));
            af[mi][0] = f2bf(lo.x); af[mi][1] = f2bf(lo.y);
            af[mi][2] = f2bf(lo.z); af[mi][3] = f2bf(lo.w);
            af[mi][4] = f2bf(hi.x); af[mi][5] = f2bf(hi.y);
            af[mi][6] = f2bf(hi.z); af[mi][7] = f2bf(hi.w);
        }
#pragma unroll
        for (int ni = 0; ni < 4; ++ni)
            bfv[ni] = *(const bf16x8*)&Bs[(wn + ni * 16 + l15) * 32 + g * 8];
#pragma unroll
        for (int mi = 0; mi < 4; ++mi)
#pragma unroll
            for (int ni = 0; ni < 4; ++ni)
                acc[mi][ni] = __builtin_amdgcn_mfma_f32_16x16x32_bf16(
                    af[mi], bfv[ni], acc[mi][ni], 0, 0, 0);
    }

    // ---- epilogue: LDS-image scatter + contiguous copy-out ----
    const int bb = bm >> 11;         // batch
    const int s0 = bm & 2047;        // 128-aligned sequence base
    __syncthreads();                 // protect A region before reuse as image
#pragma unroll
    for (int p = 0; p < 2; ++p) {
        if ((wave >> 1) == p) {
            if (z == 0) {
#pragma unroll
                for (int ni = 0; ni < 4; ++ni) {
                    const int col = wn + ni * 16 + l15;   // block-local column
                    const int hh = col >> 6, dk = col & 63;
                    char* img = SMRAW + hh * 8192;
#pragma unroll
                    for (int mi = 0; mi < 4; ++mi)
#pragma unroll
                        for (int r = 0; r < 4; ++r) {
                            const int sl = mi * 16 + 4 * g + r;
                            *(bf16*)(img + (sl * 64 + dk) * 2) =
                                f2bf(acc[mi][ni][r] * QSCALE_LOG2E);
                        }
                }
            } else if (z == 1) {
#pragma unroll
                for (int ni = 0; ni < 4; ++ni) {
                    const int col = wn + ni * 16 + l15;
                    const int hh = col >> 6, dk = col & 63;
                    const int ks = dk >> 4, h2 = (dk >> 3) & 1, e = dk & 7;
                    char* img = SMRAW + hh * 8192;
#pragma unroll
                    for (int mi = 0; mi < 4; ++mi)
#pragma unroll
                        for (int r = 0; r < 4; ++r) {
                            const int sl = mi * 16 + 4 * g + r;
                            const int t2 = sl >> 5, ql = sl & 31;
                            *(bf16*)(img + (((t2 * 4 + ks) * 64 + h2 * 32 + ql) * 8 + e) * 2) =
                                f2bf(acc[mi][ni][r]);
                        }
                }
            } else {
#pragma unroll
                for (int ni = 0; ni < 4; ++ni) {
                    const int col = wn + ni * 16 + l15;
                    const int hh = col >> 6, dv = col & 63;
                    const int dvt = dv >> 5, ql = dv & 31;
                    char* img = SMRAW + hh * 8192;
#pragma unroll
                    for (int mi = 0; mi < 4; ++mi)
#pragma unroll
                        for (int r = 0; r < 4; ++r) {
                            const int sl = mi * 16 + 4 * g + r;
                            const int ktile = sl >> 4, kk = sl & 15;
                            const int h2 = (kk >> 2) & 1;
                            const int e = (kk & 3) | ((kk >> 3) << 2);
                            *(bf16*)(img + (((dvt * 4 + ktile) * 64 + h2 * 32 + ql) * 8 + e) * 2) =
                                f2bf(acc[mi][ni][r]);
                        }
                }
            }
        }
        __syncthreads();
        {   // linear copy-out: 256 threads x 4 x (b128 read + 16B store)
            const int hh = tid >> 7, t = tid & 127;
            const int hg = (bn >> 6) + hh;              // GLOBAL head index
            const size_t a0 = (size_t)(bb * 8 + hg) * 131072;
            const size_t slab = (z == 0) ? a0 + (size_t)(s0 + p * 64) * 64
                                         : a0 + (size_t)((s0 >> 6) + p) * 4096;
            const char* img = SMRAW + hh * 8192;
#pragma unroll
            for (int i = 0; i < 4; ++i) {
                const int G = i * 128 + t;
                bf16x8 vv = *(const bf16x8*)(img + G * 16);
                *(bf16x8*)&Cb[slab + (size_t)G * 8] = vv;
            }
        }
        if (p == 0) __syncthreads();
    }
}

// ---------------- flash attention, swapped 32x32, QBLK=64/wave ----------------
__global__ __launch_bounds__(256, 2)
void k_attn(const bf16* __restrict__ Qp, const bf16* __restrict__ Khp,
            const bf16* __restrict__ Vtp, bf16* __restrict__ O)
{
    __shared__ bf16 smem[16384];   // 2 bufs x (8KB K + 8KB V)
    const int tid = threadIdx.x;
    const int l   = tid & 63;
    const int w   = tid >> 6;
    const int h   = l >> 5;
    const int ql  = l & 31;
    // XCD-chunked swizzle: xcd = d&7; 8 bh per XCD (K+V = 4MB, L2-resident)
    const int d   = blockIdx.x;
    const int bh  = ((d >> 6) << 3) | (d & 7);
    const int qt  = (d >> 3) & 7;
    const size_t base = (size_t)bh * 131072;
    const int q0 = qt * 256 + w * 64;
    const int loff = l * 16;

    // Q fragments (B-operand), two 32-row groups
    bf16x8 qfA[4], qfB[4];
#pragma unroll
    for (int ks = 0; ks < 4; ++ks) {
        qfA[ks] = *(const bf16x8*)&Qp[base + (size_t)(q0 + ql) * 64 + ks * 16 + h * 8];
        qfB[ks] = *(const bf16x8*)&Qp[base + (size_t)(q0 + 32 + ql) * 64 + ks * 16 + h * 8];
    }

    f32x16 oA0 = {}, oA1 = {}, oB0 = {}, oB1 = {};
    float lrunA = 0.f, lrunB = 0.f;

    const bf16* ksrc = Khp + base + tid * 8;
    const bf16* vsrc = Vtp + base + tid * 8;
    char* kb0 = (char*)smem;
    char* kb1 = (char*)smem + 16384;
    const int wdst = w * 1024;

    auto stage = [&](int kvt, char* kb) {
        const bf16* ks = ksrc + kvt * 4096;
        const bf16* vs = vsrc + kvt * 4096;
        gll16(ks,        kb + wdst);
        gll16(ks + 2048, kb + 4096 + wdst);
        gll16(vs,        kb + 8192 + wdst);
        gll16(vs + 2048, kb + 12288 + wdst);
    };

    auto compute = [&](const char* kb) {
        // ---- S^T = K Q^T : each A-fragment read feeds both q-groups ----
        f32x16 sA0 = {}, sA1 = {}, sB0 = {}, sB1 = {};
        __builtin_amdgcn_s_setprio(1);
#pragma unroll
        for (int ks = 0; ks < 4; ++ks) {
            bf16x8 a0 = *(const bf16x8*)(kb + ks * 1024 + loff);
            bf16x8 a1 = *(const bf16x8*)(kb + 4096 + ks * 1024 + loff);
            sA0 = __builtin_amdgcn_mfma_f32_32x32x16_bf16(a0, qfA[ks], sA0, 0, 0, 0);
            sB0 = __builtin_amdgcn_mfma_f32_32x32x16_bf16(a0, qfB[ks], sB0, 0, 0, 0);
            sA1 = __builtin_amdgcn_mfma_f32_32x32x16_bf16(a1, qfA[ks], sA1, 0, 0, 0);
            sB1 = __builtin_amdgcn_mfma_f32_32x32x16_bf16(a1, qfB[ks], sB1, 0, 0, 0);
        }
        __builtin_amdgcn_s_setprio(0);

        // ---- exp2 (native v_exp_f32) + packed lane-local partial sums ----
        f32x2 pA = {0.f, 0.f}, pB = {0.f, 0.f};
#pragma unroll
        for (int r = 0; r < 16; r += 2) {
            sA0[r]     = fexp2(sA0[r]);
            sA0[r + 1] = fexp2(sA0[r + 1]);
            sA1[r]     = fexp2(sA1[r]);
            sA1[r + 1] = fexp2(sA1[r + 1]);
            pA += (f32x2){sA0[r], sA0[r + 1]};
            pA += (f32x2){sA1[r], sA1[r + 1]};
        }
#pragma unroll
        for (int r = 0; r < 16; r += 2) {
            sB0[r]     = fexp2(sB0[r]);
            sB0[r + 1] = fexp2(sB0[r + 1]);
            sB1[r]     = fexp2(sB1[r]);
            sB1[r + 1] = fexp2(sB1[r + 1]);
            pB += (f32x2){sB0[r], sB0[r + 1]};
            pB += (f32x2){sB1[r], sB1[r + 1]};
        }
        lrunA += pA[0] + pA[1];
        lrunB += pB[0] + pB[1];

        // ---- P fragments (C/D order -> B operand) ----
        bf16x8 pbA[4], pbB[4];
#pragma unroll
        for (int j = 0; j < 4; ++j) {
            const int ofs = 8 * (j & 1);
#pragma unroll
            for (int e = 0; e < 8; ++e) {
                pbA[j][e] = f2bf((j & 2) ? sA1[ofs + e] : sA0[ofs + e]);
                pbB[j][e] = f2bf((j & 2) ? sB1[ofs + e] : sB0[ofs + e]);
            }
        }

        // ---- O^T += V^T P : each V-fragment read feeds both q-groups ----
        const char* vr = kb + 8192;
        __builtin_amdgcn_s_setprio(1);
#pragma unroll
        for (int j = 0; j < 4; ++j) {
            bf16x8 a0 = *(const bf16x8*)(vr + j * 1024 + loff);
            bf16x8 a1 = *(const bf16x8*)(vr + 4096 + j * 1024 + loff);
            oA0 = __builtin_amdgcn_mfma_f32_32x32x16_bf16(a0, pbA[j], oA0, 0, 0, 0);
            oB0 = __builtin_amdgcn_mfma_f32_32x32x16_bf16(a0, pbB[j], oB0, 0, 0, 0);
            oA1 = __builtin_amdgcn_mfma_f32_32x32x16_bf16(a1, pbA[j], oA1, 0, 0, 0);
            oB1 = __builtin_amdgcn_mfma_f32_32x32x16_bf16(a1, pbB[j], oB1, 0, 0, 0);
        }
        __builtin_amdgcn_s_setprio(0);
    };

    stage(0, kb0);
    __syncthreads();
    for (int kvt = 0; kvt < 32; kvt += 2) {
        if (kvt + 1 < 32) stage(kvt + 1, kb1);
        compute(kb0);
        __syncthreads();
        if (kvt + 2 < 32) stage(kvt + 2, kb0);
        compute(kb1);
        __syncthreads();
    }

    // ---- epilogue per q-group: normalize, transpose via per-wave LDS, store ----
    char* ot = (char*)smem + w * 4096;
    const int qr = l >> 1;
    const int dh4 = (l & 1) * 4;
    auto epi = [&](const f32x16& e0, const f32x16& e1, float lr, int qg) {
        lr += __shfl_xor(lr, 32);
        const float inv = 1.f / lr;
#pragma unroll
        for (int dvt = 0; dvt < 2; ++dvt) {
#pragma unroll
            for (int r = 0; r < 16; ++r) {
                const int dv = dvt * 32 + (r & 3) + 8 * (r >> 2) + 4 * h;
                const float val = (dvt ? e1[r] : e0[r]) * inv;
                *(bf16*)(ot + ql * 128 + ((((dv >> 3) ^ (ql & 7)) << 4) | ((dv & 7) << 1))) = f2bf(val);
            }
        }
        const size_t ob = ((size_t)(bh >> 3) * 2048 + qg + qr) * 512 + (bh & 7) * 64 + (size_t)dh4 * 8;
#pragma unroll
        for (int B = 0; B < 4; ++B) {
            bf16x8 v = *(const bf16x8*)(ot + qr * 128 + (((dh4 + B) ^ (qr & 7)) << 4));
            *(bf16x8*)&O[ob + B * 8] = v;
        }
    };
    epi(oA0, oA1, lrunA, q0);
    epi(oB0, oB1, lrunB, q0 + 32);
}

// ---------------- launch ----------------
extern "C" void kernel_launch(void* const* d_in, const int* in_sizes, int n_in,
                              void* d_out, int out_size, void* d_ws, size_t ws_size,
                              hipStream_t stream)
{
    const float* Q  = (const float*)d_in[0];
    const float* K  = (const float*)d_in[1];
    const float* V  = (const float*)d_in[2];
    const float* Wq = (const float*)d_in[3];
    const float* Wk = (const float*)d_in[4];
    const float* Wv = (const float*)d_in[5];
    const float* Wo = (const float*)d_in[6];
    const float* W1 = (const float*)d_in[7];
    const float* b1 = (const float*)d_in[8];
    const float* W2 = (const float*)d_in[9];
    const float* b2 = (const float*)d_in[10];
    float* out = (float*)d_out;

    const int M = 8 * 2048;                 // 16384 rows
    const size_t TN = (size_t)M * 512;      // 8388608 elems
    const int WN = 512 * 512;               // 262144

    char* ws = (char*)d_ws;
    bf16* Qhp  = (bf16*)ws;  // head-split, scaled
    bf16* Khp  = Qhp + TN;   // fragment-ordered K
    bf16* Vtp  = Khp + TN;   // fragment-ordered transposed V
    bf16* Vatt = Vtp + TN;
    bf16* H1   = Vatt + TN;
    bf16* Xbf  = H1 + TN;
    bf16* Wqt  = Xbf + TN;
    bf16* Wkt  = Wqt + WN;
    bf16* Wvt  = Wkt + WN;
    bf16* Wot  = Wvt + WN;
    bf16* W1b  = Wot + WN;
    bf16* W2b  = W1b + WN;

    // weight casts (LDS tile transpose, coalesced)
    k_castw<<<dim3(64, 6), 256, 0, stream>>>(Wq, Wk, Wv, Wo, W1, W2,
                                             Wqt, Wkt, Wvt, Wot, W1b, W2b);

    // fused cast+projections, k_gemm-structure, XCD-grouped (1536 blocks)
    k_proj<<<1536, 256, 0, stream>>>(Q, K, V, Wqt, Wkt, Wvt,
                                     Qhp, Khp, Vtp);

    // attention (512 blocks, 2/CU)
    k_attn<<<512, 256, 0, stream>>>(Qhp, Khp, Vtp, Vatt);

    dim3 gg(4, 128);
    // W_o + residual(Q fp32) -> Xbf
    k_gemm<1><<<gg, 256, 0, stream>>>(Vatt, Wot, nullptr, Q, nullptr, nullptr, Xbf, M, 512, 512);
    // FFN1: relu(Xbf W1^T + b1) -> H1
    k_gemm<2><<<gg, 256, 0, stream>>>(Xbf, W1b, b1, nullptr, nullptr, nullptr, H1, M, 512, 512);
    // FFN2: H1 W2^T + b2 + Xbf -> out
    k_gemm<3><<<gg, 256, 0, stream>>>(H1, W2b, b2, nullptr, Xbf, out, nullptr, M, 512, 512);
}

// Round 19
// 187.202 us; speedup vs baseline: 1.1652x; 1.0050x over previous
//
#include <hip/hip_runtime.h>
#include <stdint.h>

typedef __bf16 bf16;
typedef bf16 bf16x8 __attribute__((ext_vector_type(8)));
typedef bf16 bf16x4 __attribute__((ext_vector_type(4)));
typedef float f32x2 __attribute__((ext_vector_type(2)));
typedef float f32x4 __attribute__((ext_vector_type(4)));
typedef float f32x16 __attribute__((ext_vector_type(16)));

#define AS1 __attribute__((address_space(1)))
#define AS3 __attribute__((address_space(3)))

__device__ __forceinline__ void gll16(const void* g, void* l) {
    __builtin_amdgcn_global_load_lds((const AS1 unsigned int*)g,
                                     (AS3 unsigned int*)l, 16, 0, 0);
}

// native RTNE f32->bf16
__device__ __forceinline__ bf16 f2bf(float x) { return (bf16)x; }

// single-instruction v_exp_f32 (2^x); avoids glibc __exp2f macro collision
__device__ __forceinline__ float fexp2(float x) { return __builtin_amdgcn_exp2f(x); }

// counted vmcnt wait (T4): literal immediate, memory-clobber stops reordering
#define WAITV(N) asm volatile("s_waitcnt vmcnt(" #N ")" ::: "memory")

// QK scale folded into Q projection: (1/(8+1e-6)) * log2(e)
#define QSCALE_LOG2E 0.18033685757f

// ---------------- weight casts ----------------
// z<4: transpose-cast via LDS 64x64 tile (coalesced both sides); z>=4: straight copy
__global__ void k_castw(const float* __restrict__ Wq, const float* __restrict__ Wk,
                        const float* __restrict__ Wv, const float* __restrict__ Wo,
                        const float* __restrict__ W1, const float* __restrict__ W2,
                        bf16* __restrict__ oq, bf16* __restrict__ ok, bf16* __restrict__ ov,
                        bf16* __restrict__ oo, bf16* __restrict__ o1, bf16* __restrict__ o2)
{
    __shared__ bf16 L[64][65];
    const int z = blockIdx.y;
    const int t = threadIdx.x;
    const float* src = z == 0 ? Wq : z == 1 ? Wk : z == 2 ? Wv : z == 3 ? Wo : z == 4 ? W1 : W2;
    bf16* dst = z == 0 ? oq : z == 1 ? ok : z == 2 ? ov : z == 3 ? oo : z == 4 ? o1 : o2;
    if (z < 4) {
        const int tr = blockIdx.x >> 3, tc = blockIdx.x & 7;   // 64x64 tile
        const int r = t >> 2, c0 = (t & 3) * 16;
#pragma unroll
        for (int i = 0; i < 4; ++i) {
            float4 v = *(const float4*)(src + (size_t)(tr * 64 + r) * 512 + tc * 64 + c0 + i * 4);
            L[r][c0 + i * 4 + 0] = f2bf(v.x);
            L[r][c0 + i * 4 + 1] = f2bf(v.y);
            L[r][c0 + i * 4 + 2] = f2bf(v.z);
            L[r][c0 + i * 4 + 3] = f2bf(v.w);
        }
        __syncthreads();
        const int c2 = t >> 2, r0 = (t & 3) * 16;
        bf16* d = dst + (size_t)(tc * 64 + c2) * 512 + tr * 64 + r0;
#pragma unroll
        for (int i = 0; i < 16; ++i) d[i] = L[r0 + i][c2];
    } else {
        const size_t base = (size_t)blockIdx.x * 4096 + t * 16;
#pragma unroll
        for (int i = 0; i < 4; ++i) {
            float4 v = *(const float4*)(src + base + i * 4);
            bf16x4 o;
            o[0] = f2bf(v.x); o[1] = f2bf(v.y); o[2] = f2bf(v.z); o[3] = f2bf(v.w);
            *(bf16x4*)(dst + base + i * 4) = o;
        }
    }
}

// ---------------- shared GEMM core (bf16 A): C[128,128] += A[M,K] * Bt[N,K]^T ----------------
__device__ __forceinline__ void gemm_core(const bf16* __restrict__ A,
                                          const bf16* __restrict__ Bt,
                                          const int K, bf16* As, bf16* Bs,
                                          const int bm, const int bn,
                                          f32x4 acc[4][4])
{
    const int tid  = threadIdx.x;
    const int lane = tid & 63;
    const int wave = tid >> 6;
    const int g    = lane >> 4;
    const int l15  = lane & 15;
    const int wm   = (wave >> 1) * 64;
    const int wn   = (wave & 1) * 64;

    const int srow = tid >> 2;
    const int sk   = (tid & 3) * 8;
    const size_t aoff0 = (size_t)(bm + srow) * K + sk;
    const size_t aoff1 = (size_t)(bm + 64 + srow) * K + sk;
    const size_t boff0 = (size_t)(bn + srow) * K + sk;
    const size_t boff1 = (size_t)(bn + 64 + srow) * K + sk;
    char* asb = (char*)As + wave * 1024;
    char* bsb = (char*)Bs + wave * 1024;

    for (int kt = 0; kt < K; kt += 32) {
        __syncthreads();
        gll16(A + aoff0 + kt, asb);
        gll16(A + aoff1 + kt, asb + 4096);
        gll16(Bt + boff0 + kt, bsb);
        gll16(Bt + boff1 + kt, bsb + 4096);
        __syncthreads();
        bf16x8 af[4], bfv[4];
#pragma unroll
        for (int mi = 0; mi < 4; ++mi)
            af[mi] = *(const bf16x8*)&As[(wm + mi * 16 + l15) * 32 + g * 8];
#pragma unroll
        for (int ni = 0; ni < 4; ++ni)
            bfv[ni] = *(const bf16x8*)&Bs[(wn + ni * 16 + l15) * 32 + g * 8];
#pragma unroll
        for (int mi = 0; mi < 4; ++mi)
#pragma unroll
            for (int ni = 0; ni < 4; ++ni)
                acc[mi][ni] = __builtin_amdgcn_mfma_f32_16x16x32_bf16(
                    af[mi], bfv[ni], acc[mi][ni], 0, 0, 0);
    }
}

// ---------------- generic epilogue GEMMs ----------------
// EPI 1: Cb = bf16(acc + residf)                  (W_o + fp32 Q residual -> Xbf)
// EPI 2: Cb = bf16(relu(acc + bias[col]))         (FFN1 -> H1)
// EPI 3: Cf = acc + bias[col] + float(residb)     (FFN2 + residual -> out)
template<int EPI>
__global__ __launch_bounds__(256)
void k_gemm(const bf16* __restrict__ A, const bf16* __restrict__ Bt,
            const float* __restrict__ bias, const float* __restrict__ residf,
            const bf16* __restrict__ residb,
            float* __restrict__ Cf, bf16* __restrict__ Cb,
            int M, int N, int K)
{
    __shared__ bf16 As[128 * 32];
    __shared__ bf16 Bs[128 * 32];
    const int bm = blockIdx.y * 128, bn = blockIdx.x * 128;
    f32x4 acc[4][4] = {};
    gemm_core(A, Bt, K, As, Bs, bm, bn, acc);

    const int tid  = threadIdx.x;
    const int lane = tid & 63;
    const int wave = tid >> 6;
    const int g    = lane >> 4;
    const int l15  = lane & 15;
    const int wm   = (wave >> 1) * 64;
    const int wn   = (wave & 1) * 64;
    const int col0 = bn + wn + l15;
#pragma unroll
    for (int ni = 0; ni < 4; ++ni) {
        const int col = col0 + ni * 16;
        float bv = 0.f;
        if constexpr (EPI == 2 || EPI == 3) bv = bias[col];
#pragma unroll
        for (int mi = 0; mi < 4; ++mi) {
#pragma unroll
            for (int r = 0; r < 4; ++r) {
                const int row = bm + wm + mi * 16 + 4 * g + r;
                const size_t idx = (size_t)row * N + col;
                float v = acc[mi][ni][r];
                if constexpr (EPI == 1) {
                    Cb[idx] = f2bf(v + residf[idx]);
                } else if constexpr (EPI == 2) {
                    Cb[idx] = f2bf(fmaxf(v + bv, 0.f));
                } else {
                    Cf[idx] = v + bv + (float)residb[idx];
                }
            }
        }
    }
}

// ---------------- fused cast+projection, depth-1 counted-vmcnt pipeline ----------------
// 128x128 tile, 256 threads. 2 LDS buffers x 24KB (48KB -> 3 blocks/CU).
// Per step: issue stage(t+1) (6 gll16/thread), s_waitcnt vmcnt(6) (stage(t) done,
// stage(t+1) stays in flight), raw s_barrier, compute(t), raw s_barrier.
// NO vmcnt(0) drain in steady state. A fp32 source-swizzled; B k_gemm pattern.
// Epilogue: LDS-image scatter + contiguous copy-out (round-13, proven).
__global__ __launch_bounds__(256)
void k_proj(const float* __restrict__ Qf, const float* __restrict__ Kf, const float* __restrict__ Vf,
            const bf16* __restrict__ BQ, const bf16* __restrict__ BK, const bf16* __restrict__ BV,
            bf16* __restrict__ OQ, bf16* __restrict__ OK_, bf16* __restrict__ OV)
{
    __shared__ char SMRAW[49152];        // 2 bufs x (16KB fp32 A + 8KB bf16 B)

    // XCD-grouped decode: x = XCD slot, 4 bn-blocks of one (z,bm) adjacent per XCD
    const int dd = blockIdx.x;
    const int x = dd & 7, q = dd >> 3;
    const int bnb = q & 3;
    const int tt = x * 48 + (q >> 2);    // 0..383
    const int z  = tt >> 7;
    const int bm = (tt & 127) * 128;
    const int bn = bnb * 128;

    const float* A = z == 0 ? Qf : z == 1 ? Kf : Vf;
    const bf16* Bt = z == 0 ? BQ : z == 1 ? BK : BV;
    bf16* Cb       = z == 0 ? OQ : z == 1 ? OK_ : OV;

    const int tid  = threadIdx.x;
    const int lane = tid & 63;
    const int wave = tid >> 6;
    const int g    = lane >> 4;
    const int l15  = lane & 15;
    const int wm   = (wave >> 1) * 64;
    const int wn   = (wave & 1) * 64;

    const int krow = tid >> 3, kc = tid & 7;
    const size_t aoff = (size_t)(bm + krow) * 512 + ((kc ^ (krow & 7)) << 2);
    const int srow = tid >> 2;
    const int sk   = (tid & 3) * 8;
    const size_t boff0 = (size_t)(bn + srow) * 512 + sk;
    const size_t boff1 = (size_t)(bn + 64 + srow) * 512 + sk;

    f32x4 acc[4][4] = {};

    auto stageF = [&](int s, char* buf) {   // 6 gll16/thread per stage
        const int kt = s * 32;
#pragma unroll
        for (int j = 0; j < 4; ++j)
            gll16(A + aoff + j * 16384 + kt, buf + j * 4096 + tid * 16);
        gll16(Bt + boff0 + kt, buf + 16384 + wave * 1024);
        gll16(Bt + boff1 + kt, buf + 16384 + 4096 + wave * 1024);
    };

    auto computeF = [&](const char* buf) {
        bf16x8 af[4], bfv[4];
#pragma unroll
        for (int mi = 0; mi < 4; ++mi) {
            const int row = wm + mi * 16 + l15;
            const int r7 = row & 7;
            float4 lo = *(const float4*)(buf + row * 128 + (((2 * g) ^ r7) << 4));
            float4 hi = *(const float4*)(buf + row * 128 + (((2 * g + 1) ^ r7) << 4));
            af[mi][0] = f2bf(lo.x); af[mi][1] = f2bf(lo.y);
            af[mi][2] = f2bf(lo.z); af[mi][3] = f2bf(lo.w);
            af[mi][4] = f2bf(hi.x); af[mi][5] = f2bf(hi.y);
            af[mi][6] = f2bf(hi.z); af[mi][7] = f2bf(hi.w);
        }
#pragma unroll
        for (int ni = 0; ni < 4; ++ni)
            bfv[ni] = *(const bf16x8*)(buf + 16384 +
                        ((wn + ni * 16 + l15) * 32 + g * 8) * 2);
#pragma unroll
        for (int mi = 0; mi < 4; ++mi)
#pragma unroll
            for (int ni = 0; ni < 4; ++ni)
                acc[mi][ni] = __builtin_amdgcn_mfma_f32_16x16x32_bf16(
                    af[mi], bfv[ni], acc[mi][ni], 0, 0, 0);
    };

    // prologue: stage(0) in flight
    stageF(0, SMRAW);
#pragma unroll
    for (int t = 0; t < 16; ++t) {
        if (t + 1 < 16) {
            stageF(t + 1, SMRAW + ((t + 1) & 1) * 24576);
            WAITV(6);                        // stage(t) complete; t+1 stays in flight
        } else {
            WAITV(0);                        // final stage drain
        }
        __builtin_amdgcn_s_barrier();        // all waves' stage(t) writes visible
        __builtin_amdgcn_sched_barrier(0);
        computeF(SMRAW + (t & 1) * 24576);
        __builtin_amdgcn_s_barrier();        // nobody still reads buf(t) when t+2 overwrites
    }

    // ---- epilogue: LDS-image scatter + contiguous copy-out ----
    const int bb = bm >> 11;         // batch
    const int s0 = bm & 2047;        // 128-aligned sequence base
    __syncthreads();                 // full fence before reusing SMRAW as image
#pragma unroll
    for (int p = 0; p < 2; ++p) {
        if ((wave >> 1) == p) {
            if (z == 0) {
#pragma unroll
                for (int ni = 0; ni < 4; ++ni) {
                    const int col = wn + ni * 16 + l15;   // block-local column
                    const int hh = col >> 6, dk = col & 63;
                    char* img = SMRAW + hh * 8192;
#pragma unroll
                    for (int mi = 0; mi < 4; ++mi)
#pragma unroll
                        for (int r = 0; r < 4; ++r) {
                            const int sl = mi * 16 + 4 * g + r;
                            *(bf16*)(img + (sl * 64 + dk) * 2) =
                                f2bf(acc[mi][ni][r] * QSCALE_LOG2E);
                        }
                }
            } else if (z == 1) {
#pragma unroll
                for (int ni = 0; ni < 4; ++ni) {
                    const int col = wn + ni * 16 + l15;
                    const int hh = col >> 6, dk = col & 63;
                    const int ks = dk >> 4, h2 = (dk >> 3) & 1, e = dk & 7;
                    char* img = SMRAW + hh * 8192;
#pragma unroll
                    for (int mi = 0; mi < 4; ++mi)
#pragma unroll
                        for (int r = 0; r < 4; ++r) {
                            const int sl = mi * 16 + 4 * g + r;
                            const int t2 = sl >> 5, ql = sl & 31;
                            *(bf16*)(img + (((t2 * 4 + ks) * 64 + h2 * 32 + ql) * 8 + e) * 2) =
                                f2bf(acc[mi][ni][r]);
                        }
                }
            } else {
#pragma unroll
                for (int ni = 0; ni < 4; ++ni) {
                    const int col = wn + ni * 16 + l15;
                    const int hh = col >> 6, dv = col & 63;
                    const int dvt = dv >> 5, ql = dv & 31;
                    char* img = SMRAW + hh * 8192;
#pragma unroll
                    for (int mi = 0; mi < 4; ++mi)
#pragma unroll
                        for (int r = 0; r < 4; ++r) {
                            const int sl = mi * 16 + 4 * g + r;
                            const int ktile = sl >> 4, kk = sl & 15;
                            const int h2 = (kk >> 2) & 1;
                            const int e = (kk & 3) | ((kk >> 3) << 2);
                            *(bf16*)(img + (((dvt * 4 + ktile) * 64 + h2 * 32 + ql) * 8 + e) * 2) =
                                f2bf(acc[mi][ni][r]);
                        }
                }
            }
        }
        __syncthreads();
        {   // linear copy-out: 256 threads x 4 x (b128 read + 16B store)
            const int hh = tid >> 7, t = tid & 127;
            const int hg = (bn >> 6) + hh;              // GLOBAL head index
            const size_t a0 = (size_t)(bb * 8 + hg) * 131072;
            const size_t slab = (z == 0) ? a0 + (size_t)(s0 + p * 64) * 64
                                         : a0 + (size_t)((s0 >> 6) + p) * 4096;
            const char* img = SMRAW + hh * 8192;
#pragma unroll
            for (int i = 0; i < 4; ++i) {
                const int G = i * 128 + t;
                bf16x8 vv = *(const bf16x8*)(img + G * 16);
                *(bf16x8*)&Cb[slab + (size_t)G * 8] = vv;
            }
        }
        if (p == 0) __syncthreads();
    }
}

// ---------------- flash attention, swapped 32x32, QBLK=64/wave ----------------
__global__ __launch_bounds__(256, 2)
void k_attn(const bf16* __restrict__ Qp, const bf16* __restrict__ Khp,
            const bf16* __restrict__ Vtp, bf16* __restrict__ O)
{
    __shared__ bf16 smem[16384];   // 2 bufs x (8KB K + 8KB V)
    const int tid = threadIdx.x;
    const int l   = tid & 63;
    const int w   = tid >> 6;
    const int h   = l >> 5;
    const int ql  = l & 31;
    // XCD-chunked swizzle: xcd = d&7; 8 bh per XCD (K+V = 4MB, L2-resident)
    const int d   = blockIdx.x;
    const int bh  = ((d >> 6) << 3) | (d & 7);
    const int qt  = (d >> 3) & 7;
    const size_t base = (size_t)bh * 131072;
    const int q0 = qt * 256 + w * 64;
    const int loff = l * 16;

    // Q fragments (B-operand), two 32-row groups
    bf16x8 qfA[4], qfB[4];
#pragma unroll
    for (int ks = 0; ks < 4; ++ks) {
        qfA[ks] = *(const bf16x8*)&Qp[base + (size_t)(q0 + ql) * 64 + ks * 16 + h * 8];
        qfB[ks] = *(const bf16x8*)&Qp[base + (size_t)(q0 + 32 + ql) * 64 + ks * 16 + h * 8];
    }

    f32x16 oA0 = {}, oA1 = {}, oB0 = {}, oB1 = {};
    float lrunA = 0.f, lrunB = 0.f;

    const bf16* ksrc = Khp + base + tid * 8;
    const bf16* vsrc = Vtp + base + tid * 8;
    char* kb0 = (char*)smem;
    char* kb1 = (char*)smem + 16384;
    const int wdst = w * 1024;

    auto stage = [&](int kvt, char* kb) {
        const bf16* ks = ksrc + kvt * 4096;
        const bf16* vs = vsrc + kvt * 4096;
        gll16(ks,        kb + wdst);
        gll16(ks + 2048, kb + 4096 + wdst);
        gll16(vs,        kb + 8192 + wdst);
        gll16(vs + 2048, kb + 12288 + wdst);
    };

    auto compute = [&](const char* kb) {
        // ---- S^T = K Q^T : each A-fragment read feeds both q-groups ----
        f32x16 sA0 = {}, sA1 = {}, sB0 = {}, sB1 = {};
        __builtin_amdgcn_s_setprio(1);
#pragma unroll
        for (int ks = 0; ks < 4; ++ks) {
            bf16x8 a0 = *(const bf16x8*)(kb + ks * 1024 + loff);
            bf16x8 a1 = *(const bf16x8*)(kb + 4096 + ks * 1024 + loff);
            sA0 = __builtin_amdgcn_mfma_f32_32x32x16_bf16(a0, qfA[ks], sA0, 0, 0, 0);
            sB0 = __builtin_amdgcn_mfma_f32_32x32x16_bf16(a0, qfB[ks], sB0, 0, 0, 0);
            sA1 = __builtin_amdgcn_mfma_f32_32x32x16_bf16(a1, qfA[ks], sA1, 0, 0, 0);
            sB1 = __builtin_amdgcn_mfma_f32_32x32x16_bf16(a1, qfB[ks], sB1, 0, 0, 0);
        }
        __builtin_amdgcn_s_setprio(0);

        // ---- exp2 (native v_exp_f32) + packed lane-local partial sums ----
        f32x2 pA = {0.f, 0.f}, pB = {0.f, 0.f};
#pragma unroll
        for (int r = 0; r < 16; r += 2) {
            sA0[r]     = fexp2(sA0[r]);
            sA0[r + 1] = fexp2(sA0[r + 1]);
            sA1[r]     = fexp2(sA1[r]);
            sA1[r + 1] = fexp2(sA1[r + 1]);
            pA += (f32x2){sA0[r], sA0[r + 1]};
            pA += (f32x2){sA1[r], sA1[r + 1]};
        }
#pragma unroll
        for (int r = 0; r < 16; r += 2) {
            sB0[r]     = fexp2(sB0[r]);
            sB0[r + 1] = fexp2(sB0[r + 1]);
            sB1[r]     = fexp2(sB1[r]);
            sB1[r + 1] = fexp2(sB1[r + 1]);
            pB += (f32x2){sB0[r], sB0[r + 1]};
            pB += (f32x2){sB1[r], sB1[r + 1]};
        }
        lrunA += pA[0] + pA[1];
        lrunB += pB[0] + pB[1];

        // ---- P fragments (C/D order -> B operand) ----
        bf16x8 pbA[4], pbB[4];
#pragma unroll
        for (int j = 0; j < 4; ++j) {
            const int ofs = 8 * (j & 1);
#pragma unroll
            for (int e = 0; e < 8; ++e) {
                pbA[j][e] = f2bf((j & 2) ? sA1[ofs + e] : sA0[ofs + e]);
                pbB[j][e] = f2bf((j & 2) ? sB1[ofs + e] : sB0[ofs + e]);
            }
        }

        // ---- O^T += V^T P : each V-fragment read feeds both q-groups ----
        const char* vr = kb + 8192;
        __builtin_amdgcn_s_setprio(1);
#pragma unroll
        for (int j = 0; j < 4; ++j) {
            bf16x8 a0 = *(const bf16x8*)(vr + j * 1024 + loff);
            bf16x8 a1 = *(const bf16x8*)(vr + 4096 + j * 1024 + loff);
            oA0 = __builtin_amdgcn_mfma_f32_32x32x16_bf16(a0, pbA[j], oA0, 0, 0, 0);
            oB0 = __builtin_amdgcn_mfma_f32_32x32x16_bf16(a0, pbB[j], oB0, 0, 0, 0);
            oA1 = __builtin_amdgcn_mfma_f32_32x32x16_bf16(a1, pbA[j], oA1, 0, 0, 0);
            oB1 = __builtin_amdgcn_mfma_f32_32x32x16_bf16(a1, pbB[j], oB1, 0, 0, 0);
        }
        __builtin_amdgcn_s_setprio(0);
    };

    stage(0, kb0);
    __syncthreads();
    for (int kvt = 0; kvt < 32; kvt += 2) {
        if (kvt + 1 < 32) stage(kvt + 1, kb1);
        compute(kb0);
        __syncthreads();
        if (kvt + 2 < 32) stage(kvt + 2, kb0);
        compute(kb1);
        __syncthreads();
    }

    // ---- epilogue per q-group: normalize, transpose via per-wave LDS, store ----
    char* ot = (char*)smem + w * 4096;
    const int qr = l >> 1;
    const int dh4 = (l & 1) * 4;
    auto epi = [&](const f32x16& e0, const f32x16& e1, float lr, int qg) {
        lr += __shfl_xor(lr, 32);
        const float inv = 1.f / lr;
#pragma unroll
        for (int dvt = 0; dvt < 2; ++dvt) {
#pragma unroll
            for (int r = 0; r < 16; ++r) {
                const int dv = dvt * 32 + (r & 3) + 8 * (r >> 2) + 4 * h;
                const float val = (dvt ? e1[r] : e0[r]) * inv;
                *(bf16*)(ot + ql * 128 + ((((dv >> 3) ^ (ql & 7)) << 4) | ((dv & 7) << 1))) = f2bf(val);
            }
        }
        const size_t ob = ((size_t)(bh >> 3) * 2048 + qg + qr) * 512 + (bh & 7) * 64 + (size_t)dh4 * 8;
#pragma unroll
        for (int B = 0; B < 4; ++B) {
            bf16x8 v = *(const bf16x8*)(ot + qr * 128 + (((dh4 + B) ^ (qr & 7)) << 4));
            *(bf16x8*)&O[ob + B * 8] = v;
        }
    };
    epi(oA0, oA1, lrunA, q0);
    epi(oB0, oB1, lrunB, q0 + 32);
}

// ---------------- launch ----------------
extern "C" void kernel_launch(void* const* d_in, const int* in_sizes, int n_in,
                              void* d_out, int out_size, void* d_ws, size_t ws_size,
                              hipStream_t stream)
{
    const float* Q  = (const float*)d_in[0];
    const float* K  = (const float*)d_in[1];
    const float* V  = (const float*)d_in[2];
    const float* Wq = (const float*)d_in[3];
    const float* Wk = (const float*)d_in[4];
    const float* Wv = (const float*)d_in[5];
    const float* Wo = (const float*)d_in[6];
    const float* W1 = (const float*)d_in[7];
    const float* b1 = (const float*)d_in[8];
    const float* W2 = (const float*)d_in[9];
    const float* b2 = (const float*)d_in[10];
    float* out = (float*)d_out;

    const int M = 8 * 2048;                 // 16384 rows
    const size_t TN = (size_t)M * 512;      // 8388608 elems
    const int WN = 512 * 512;               // 262144

    char* ws = (char*)d_ws;
    bf16* Qhp  = (bf16*)ws;  // head-split, scaled
    bf16* Khp  = Qhp + TN;   // fragment-ordered K
    bf16* Vtp  = Khp + TN;   // fragment-ordered transposed V
    bf16* Vatt = Vtp + TN;
    bf16* H1   = Vatt + TN;
    bf16* Xbf  = H1 + TN;
    bf16* Wqt  = Xbf + TN;
    bf16* Wkt  = Wqt + WN;
    bf16* Wvt  = Wkt + WN;
    bf16* Wot  = Wvt + WN;
    bf16* W1b  = Wot + WN;
    bf16* W2b  = W1b + WN;

    // weight casts (LDS tile transpose, coalesced)
    k_castw<<<dim3(64, 6), 256, 0, stream>>>(Wq, Wk, Wv, Wo, W1, W2,
                                             Wqt, Wkt, Wvt, Wot, W1b, W2b);

    // fused cast+projections, depth-1 counted-vmcnt pipeline, XCD-grouped (1536 blocks)
    k_proj<<<1536, 256, 0, stream>>>(Q, K, V, Wqt, Wkt, Wvt,
                                     Qhp, Khp, Vtp);

    // attention (512 blocks, 2/CU)
    k_attn<<<512, 256, 0, stream>>>(Qhp, Khp, Vtp, Vatt);

    dim3 gg(4, 128);
    // W_o + residual(Q fp32) -> Xbf
    k_gemm<1><<<gg, 256, 0, stream>>>(Vatt, Wot, nullptr, Q, nullptr, nullptr, Xbf, M, 512, 512);
    // FFN1: relu(Xbf W1^T + b1) -> H1
    k_gemm<2><<<gg, 256, 0, stream>>>(Xbf, W1b, b1, nullptr, nullptr, nullptr, H1, M, 512, 512);
    // FFN2: H1 W2^T + b2 + Xbf -> out
    k_gemm<3><<<gg, 256, 0, stream>>>(H1, W2b, b2, nullptr, Xbf, out, nullptr, M, 512, 512);
}